// Round 1
// baseline (386.905 us; speedup 1.0000x reference)
//
#include <hip/hip_runtime.h>
#include <hip/hip_bf16.h>

#define L_DIM 8192
#define H_DIM 512
#define P_DIM 512
#define CHUNK 64
#define NCHUNK (L_DIM / CHUNK)   // 128

// ---------------------------------------------------------------------------
// K0: discretization. One block per p.
//   Lambda_bar = exp(Lambda*Delta); factor f = (Lambda_bar-1)/Lambda
//   Bcat[2p][h] = Re(f*B~), Bcat[2p+1][h] = Im(f*B~)
//   lambda_bar (float2 per p), lambda_powN = exp(CHUNK*Lambda*Delta)
// ---------------------------------------------------------------------------
__global__ void k_discretize(const float* __restrict__ Lre, const float* __restrict__ Lim,
                             const float* __restrict__ Bin, const float* __restrict__ log_step,
                             float* __restrict__ Bcat, float* __restrict__ lambda_bar,
                             float* __restrict__ lambda_powN) {
    int p = blockIdx.x;
    float lr = Lre[p], li = Lim[p];
    float dt = expf(log_step[p]);
    float ar = lr * dt, ai = li * dt;          // Lambda*Delta
    float er = expf(ar);
    float lbr = er * cosf(ai);
    float lbi = er * sinf(ai);
    // f = (lambda_bar - 1) / Lambda
    float nr = lbr - 1.0f, ni = lbi;
    float den = lr * lr + li * li;
    float fr = (nr * lr + ni * li) / den;
    float fi = (ni * lr - nr * li) / den;
    if (threadIdx.x == 0) {
        lambda_bar[2 * p] = lbr;
        lambda_bar[2 * p + 1] = lbi;
        float eN = expf(ar * (float)CHUNK);
        lambda_powN[2 * p] = eN * cosf(ai * (float)CHUNK);
        lambda_powN[2 * p + 1] = eN * sinf(ai * (float)CHUNK);
    }
    for (int h = threadIdx.x; h < H_DIM; h += blockDim.x) {
        float br = Bin[((size_t)p * H_DIM + h) * 2 + 0];
        float bi = Bin[((size_t)p * H_DIM + h) * 2 + 1];
        float Br = fr * br - fi * bi;
        float Bi = fr * bi + fi * br;
        Bcat[(size_t)(2 * p) * H_DIM + h] = Br;
        Bcat[(size_t)(2 * p + 1) * H_DIM + h] = Bi;
    }
}

// ---------------------------------------------------------------------------
// K0b: Ccat[h][2p] = C_re[h][p], Ccat[h][2p+1] = -C_im[h][p]
// ---------------------------------------------------------------------------
__global__ void k_build_ccat(const float* __restrict__ Cin, float* __restrict__ Ccat) {
    int idx = blockIdx.x * blockDim.x + threadIdx.x;   // over H*P
    if (idx >= H_DIM * P_DIM) return;
    int h = idx / P_DIM, p = idx % P_DIM;
    float cr = Cin[(size_t)idx * 2 + 0];
    float ci = Cin[(size_t)idx * 2 + 1];
    Ccat[(size_t)h * (2 * P_DIM) + 2 * p + 0] = cr;
    Ccat[(size_t)h * (2 * P_DIM) + 2 * p + 1] = -ci;
}

// ---------------------------------------------------------------------------
// Tiled fp32 GEMM: out[M][N] = A[M][K] * B[N][K]^T  (row-major A, B)
// Optional epilogue (GEMM2): out += Dv[n] * U[m][n]
// BM=BN=64, BK=16, 256 threads, 4x4 per thread. All dims divide tiles exactly.
// ---------------------------------------------------------------------------
template <bool EPI>
__global__ __launch_bounds__(256) void k_gemm_abt(const float* __restrict__ A,
                                                  const float* __restrict__ B,
                                                  float* __restrict__ Cout,
                                                  int M, int N, int K,
                                                  const float* __restrict__ Dv,
                                                  const float* __restrict__ U) {
    __shared__ float As[16][64 + 1];
    __shared__ float Bs[16][64 + 1];
    int tid = threadIdx.x;
    int tx = tid & 15;          // 0..15 -> col group
    int ty = tid >> 4;          // 0..15 -> row group
    int bm = blockIdx.y * 64;
    int bn = blockIdx.x * 64;
    int lrow = tid >> 2;        // 0..63
    int lk4 = (tid & 3) * 4;    // 0,4,8,12

    float acc[4][4] = {};

    for (int kk = 0; kk < K; kk += 16) {
        float4 av = *(const float4*)(A + (size_t)(bm + lrow) * K + kk + lk4);
        float4 bv = *(const float4*)(B + (size_t)(bn + lrow) * K + kk + lk4);
        As[lk4 + 0][lrow] = av.x; As[lk4 + 1][lrow] = av.y;
        As[lk4 + 2][lrow] = av.z; As[lk4 + 3][lrow] = av.w;
        Bs[lk4 + 0][lrow] = bv.x; Bs[lk4 + 1][lrow] = bv.y;
        Bs[lk4 + 2][lrow] = bv.z; Bs[lk4 + 3][lrow] = bv.w;
        __syncthreads();
#pragma unroll
        for (int k = 0; k < 16; ++k) {
            float a0 = As[k][ty * 4 + 0], a1 = As[k][ty * 4 + 1];
            float a2 = As[k][ty * 4 + 2], a3 = As[k][ty * 4 + 3];
            float b0 = Bs[k][tx * 4 + 0], b1 = Bs[k][tx * 4 + 1];
            float b2 = Bs[k][tx * 4 + 2], b3 = Bs[k][tx * 4 + 3];
            acc[0][0] += a0 * b0; acc[0][1] += a0 * b1; acc[0][2] += a0 * b2; acc[0][3] += a0 * b3;
            acc[1][0] += a1 * b0; acc[1][1] += a1 * b1; acc[1][2] += a1 * b2; acc[1][3] += a1 * b3;
            acc[2][0] += a2 * b0; acc[2][1] += a2 * b1; acc[2][2] += a2 * b2; acc[2][3] += a2 * b3;
            acc[3][0] += a3 * b0; acc[3][1] += a3 * b1; acc[3][2] += a3 * b2; acc[3][3] += a3 * b3;
        }
        __syncthreads();
    }

#pragma unroll
    for (int i = 0; i < 4; ++i) {
#pragma unroll
        for (int j = 0; j < 4; ++j) {
            int m = bm + ty * 4 + i;
            int n = bn + tx * 4 + j;
            float v = acc[i][j];
            if (EPI) v += Dv[n] * U[(size_t)m * N + n];
            Cout[(size_t)m * N + n] = v;
        }
    }
}

// ---------------------------------------------------------------------------
// Scan kernels. Bu viewed as float2[L][P]. Chunked scan over L.
// ---------------------------------------------------------------------------
__global__ __launch_bounds__(512) void k_scan_summary(const float* __restrict__ Bu,
                                                      const float* __restrict__ lambda_bar,
                                                      float* __restrict__ S) {
    int p = threadIdx.x;       // 0..511
    int c = blockIdx.x;        // 0..NCHUNK-1
    float lr = lambda_bar[2 * p], li = lambda_bar[2 * p + 1];
    float xr = 0.f, xi = 0.f;
    const float2* bu = (const float2*)Bu + (size_t)c * CHUNK * P_DIM + p;
#pragma unroll 4
    for (int j = 0; j < CHUNK; ++j) {
        float2 b = bu[(size_t)j * P_DIM];
        float nxr = lr * xr - li * xi + b.x;
        float nxi = lr * xi + li * xr + b.y;
        xr = nxr; xi = nxi;
    }
    ((float2*)S)[(size_t)c * P_DIM + p] = make_float2(xr, xi);
}

__global__ __launch_bounds__(512) void k_scan_combine(const float* __restrict__ S,
                                                      const float* __restrict__ lambda_powN,
                                                      float* __restrict__ prefix) {
    int p = threadIdx.x;       // single block of 512
    float lr = lambda_powN[2 * p], li = lambda_powN[2 * p + 1];
    float xr = 0.f, xi = 0.f;
    for (int c = 0; c < NCHUNK; ++c) {
        ((float2*)prefix)[(size_t)c * P_DIM + p] = make_float2(xr, xi);
        float2 s = ((const float2*)S)[(size_t)c * P_DIM + p];
        float nxr = lr * xr - li * xi + s.x;
        float nxi = lr * xi + li * xr + s.y;
        xr = nxr; xi = nxi;
    }
}

__global__ __launch_bounds__(512) void k_scan_apply(float* __restrict__ Bu,       // in-place -> xs
                                                    const float* __restrict__ lambda_bar,
                                                    const float* __restrict__ prefix) {
    int p = threadIdx.x;
    int c = blockIdx.x;
    float lr = lambda_bar[2 * p], li = lambda_bar[2 * p + 1];
    float2 x0 = ((const float2*)prefix)[(size_t)c * P_DIM + p];
    float xr = x0.x, xi = x0.y;
    float2* bu = (float2*)Bu + (size_t)c * CHUNK * P_DIM + p;
#pragma unroll 4
    for (int j = 0; j < CHUNK; ++j) {
        float2 b = bu[(size_t)j * P_DIM];
        float nxr = lr * xr - li * xi + b.x;
        float nxi = lr * xi + li * xr + b.y;
        xr = nxr; xi = nxi;
        bu[(size_t)j * P_DIM] = make_float2(xr, xi);
    }
}

// ---------------------------------------------------------------------------
extern "C" void kernel_launch(void* const* d_in, const int* in_sizes, int n_in,
                              void* d_out, int out_size, void* d_ws, size_t ws_size,
                              hipStream_t stream) {
    const float* u        = (const float*)d_in[0];
    const float* Lre      = (const float*)d_in[1];
    const float* Lim      = (const float*)d_in[2];
    const float* Bin      = (const float*)d_in[3];
    const float* Cin      = (const float*)d_in[4];
    const float* Dv       = (const float*)d_in[5];
    const float* log_step = (const float*)d_in[6];
    float* y = (float*)d_out;

    float* ws = (float*)d_ws;
    float* Bcat = ws;                                  // 2P*H           = 524288
    float* Ccat = Bcat + (size_t)2 * P_DIM * H_DIM;    // H*2P           = 524288
    float* Bu   = Ccat + (size_t)2 * P_DIM * H_DIM;    // L*2P           = 8388608 (xs in-place)
    float* lamb = Bu + (size_t)L_DIM * 2 * P_DIM;      // 2P
    float* lamN = lamb + 2 * P_DIM;                    // 2P
    float* S    = lamN + 2 * P_DIM;                    // NCHUNK*2P      = 131072
    float* pref = S + (size_t)NCHUNK * 2 * P_DIM;      // NCHUNK*2P      = 131072

    // K0: discretize
    k_discretize<<<P_DIM, 256, 0, stream>>>(Lre, Lim, Bin, log_step, Bcat, lamb, lamN);
    // K0b: Ccat
    k_build_ccat<<<(H_DIM * P_DIM + 255) / 256, 256, 0, stream>>>(Cin, Ccat);
    // GEMM1: Bu[L][2P] = u[L][H] * Bcat[2P][H]^T
    k_gemm_abt<false><<<dim3((2 * P_DIM) / 64, L_DIM / 64), 256, 0, stream>>>(
        u, Bcat, Bu, L_DIM, 2 * P_DIM, H_DIM, nullptr, nullptr);
    // Scan
    k_scan_summary<<<NCHUNK, 512, 0, stream>>>(Bu, lamb, S);
    k_scan_combine<<<1, 512, 0, stream>>>(S, lamN, pref);
    k_scan_apply<<<NCHUNK, 512, 0, stream>>>(Bu, lamb, pref);
    // GEMM2: y[L][H] = xs[L][2P] * Ccat[H][2P]^T + D*u
    k_gemm_abt<true><<<dim3(H_DIM / 64, L_DIM / 64), 256, 0, stream>>>(
        Bu, Ccat, y, L_DIM, H_DIM, 2 * P_DIM, Dv, u);
}

// Round 2
// 117.291 us; speedup vs baseline: 3.2987x; 3.2987x over previous
//
#include <hip/hip_runtime.h>
#include <hip/hip_bf16.h>

#define L_DIM 8192
#define H_DIM 512
#define P_DIM 512
#define CHUNK 64
#define NCHUNK (L_DIM / CHUNK)   // 128

typedef __attribute__((ext_vector_type(8))) short bf16x8;
typedef __attribute__((ext_vector_type(4))) float f32x4;

__device__ inline short f2bf(float x) {
    union { float f; unsigned u; } v; v.f = x;
    unsigned r = v.u + 0x7fffu + ((v.u >> 16) & 1u);
    return (short)(r >> 16);
}

__device__ inline void gload_lds16(const void* g, void* l) {
    __builtin_amdgcn_global_load_lds(
        (const __attribute__((address_space(1))) unsigned int*)g,
        (__attribute__((address_space(3))) unsigned int*)l, 16, 0, 0);
}

// ---------------------------------------------------------------------------
// K0: discretization -> Bcat (bf16), lambda_bar, lambda_powN
//   Bcat[2p][h] = Re(f*B~), Bcat[2p+1][h] = Im(f*B~),  f = (exp(L*dt)-1)/L
// ---------------------------------------------------------------------------
__global__ void k_discretize(const float* __restrict__ Lre, const float* __restrict__ Lim,
                             const float* __restrict__ Bin, const float* __restrict__ log_step,
                             short* __restrict__ Bcat, float* __restrict__ lambda_bar,
                             float* __restrict__ lambda_powN) {
    int p = blockIdx.x;
    float lr = Lre[p], li = Lim[p];
    float dt = expf(log_step[p]);
    float ar = lr * dt, ai = li * dt;          // Lambda*Delta
    float er = expf(ar);
    float lbr = er * cosf(ai);
    float lbi = er * sinf(ai);
    float nr = lbr - 1.0f, ni = lbi;
    float den = lr * lr + li * li;
    float fr = (nr * lr + ni * li) / den;
    float fi = (ni * lr - nr * li) / den;
    if (threadIdx.x == 0) {
        lambda_bar[2 * p] = lbr;
        lambda_bar[2 * p + 1] = lbi;
        float eN = expf(ar * (float)CHUNK);
        lambda_powN[2 * p] = eN * cosf(ai * (float)CHUNK);
        lambda_powN[2 * p + 1] = eN * sinf(ai * (float)CHUNK);
    }
    for (int h = threadIdx.x; h < H_DIM; h += blockDim.x) {
        float br = Bin[((size_t)p * H_DIM + h) * 2 + 0];
        float bi = Bin[((size_t)p * H_DIM + h) * 2 + 1];
        float Br = fr * br - fi * bi;
        float Bi = fr * bi + fi * br;
        Bcat[(size_t)(2 * p) * H_DIM + h] = f2bf(Br);
        Bcat[(size_t)(2 * p + 1) * H_DIM + h] = f2bf(Bi);
    }
}

// Ccat[h][2p] = C_re[h][p], Ccat[h][2p+1] = -C_im[h][p]   (bf16)
__global__ void k_build_ccat(const float* __restrict__ Cin, short* __restrict__ Ccat) {
    int idx = blockIdx.x * blockDim.x + threadIdx.x;   // over H*P
    if (idx >= H_DIM * P_DIM) return;
    int h = idx / P_DIM, p = idx % P_DIM;
    float cr = Cin[(size_t)idx * 2 + 0];
    float ci = Cin[(size_t)idx * 2 + 1];
    Ccat[(size_t)h * (2 * P_DIM) + 2 * p + 0] = f2bf(cr);
    Ccat[(size_t)h * (2 * P_DIM) + 2 * p + 1] = f2bf(-ci);
}

// ---------------------------------------------------------------------------
// MFMA GEMM: Cout[M][N] = A[M][K](fp32, converted to bf16 in staging)
//                         * B[N][K](bf16)^T
// 128x128 tile, BK=32, 4 waves, 16x16x32 bf16 MFMA, 4x4 frags/wave.
// B staged via global_load_lds (16B); A reg-staged fp32->bf16 + ds_write_b64.
// EPI: Cout += Dv[n] * U[m][n]
// ---------------------------------------------------------------------------
template<bool EPI>
__global__ __launch_bounds__(256) void k_gemm_f32a_bf16b(
        const float* __restrict__ A, const short* __restrict__ B,
        float* __restrict__ Cout, int M, int N, int K,
        const float* __restrict__ Dv, const float* __restrict__ U) {
    __shared__ short As[128 * 32];
    __shared__ short Bs[128 * 32];
    const int tid = threadIdx.x;
    const int lane = tid & 63;
    const int wid = tid >> 6;
    const int wr = wid >> 1, wc = wid & 1;
    const int bm = blockIdx.y * 128;
    const int bn = blockIdx.x * 128;

    // B staging geometry (per wave, 2 insts of 16B/lane -> 1024B each)
    const int bg = wid * 2048 + lane * 16;       // byte idx in 8KB tile, q=0
    const int brow_g = bg >> 6;                  // tile row (64B rows)
    const int bcol_b = bg & 63;                  // byte within row

    f32x4 acc[4][4] = {};

    const int arow = wr * 64 + (lane & 15);
    const int brow = wc * 64 + (lane & 15);
    const int kgrp = (lane >> 4) * 8;

    for (int kk = 0; kk < K; kk += 32) {
        // B: async global -> LDS (bf16 already)
        {
            const char* s0 = (const char*)B + ((size_t)(bn + brow_g) * K + kk) * 2 + bcol_b;
            gload_lds16(s0, (char*)Bs + wid * 2048 + lane * 16);
            const char* s1 = (const char*)B + ((size_t)(bn + brow_g + 16) * K + kk) * 2 + bcol_b;
            gload_lds16(s1, (char*)Bs + wid * 2048 + 1024 + lane * 16);
        }
        // A: fp32 load -> bf16 convert -> LDS
#pragma unroll
        for (int q = 0; q < 4; ++q) {
            int f = q * 256 + tid;               // float4 index in 128x32 tile
            int row = f >> 3, c4 = f & 7;
            float4 av = *(const float4*)(A + (size_t)(bm + row) * K + kk + c4 * 4);
            short4 sv = make_short4(f2bf(av.x), f2bf(av.y), f2bf(av.z), f2bf(av.w));
            *(short4*)&As[row * 32 + c4 * 4] = sv;
        }
        __syncthreads();
        bf16x8 af[4], bfr[4];
#pragma unroll
        for (int m = 0; m < 4; ++m) af[m] = *(const bf16x8*)&As[(arow + m * 16) * 32 + kgrp];
#pragma unroll
        for (int n = 0; n < 4; ++n) bfr[n] = *(const bf16x8*)&Bs[(brow + n * 16) * 32 + kgrp];
#pragma unroll
        for (int m = 0; m < 4; ++m)
#pragma unroll
            for (int n = 0; n < 4; ++n)
                acc[m][n] = __builtin_amdgcn_mfma_f32_16x16x32_bf16(af[m], bfr[n], acc[m][n], 0, 0, 0);
        __syncthreads();
    }

    const int fq = lane >> 4, fr = lane & 15;
#pragma unroll
    for (int m = 0; m < 4; ++m) {
#pragma unroll
        for (int n = 0; n < 4; ++n) {
            int col = bn + wc * 64 + n * 16 + fr;
            int row0 = bm + wr * 64 + m * 16 + fq * 4;
#pragma unroll
            for (int j = 0; j < 4; ++j) {
                int row = row0 + j;
                float v = acc[m][n][j];
                if (EPI) v += Dv[col] * U[(size_t)row * N + col];
                Cout[(size_t)row * N + col] = v;
            }
        }
    }
}

// ---------------------------------------------------------------------------
// Scan kernels. Bu viewed as float2[L][P]. Chunked scan over L.
// ---------------------------------------------------------------------------
__global__ __launch_bounds__(256) void k_scan_summary(const float* __restrict__ Bu,
                                                      const float* __restrict__ lambda_bar,
                                                      float* __restrict__ S) {
    int gid = blockIdx.x * blockDim.x + threadIdx.x;   // NCHUNK*P threads
    int c = gid >> 9, p = gid & 511;
    float lr = lambda_bar[2 * p], li = lambda_bar[2 * p + 1];
    float xr = 0.f, xi = 0.f;
    const float2* bu = (const float2*)Bu + (size_t)c * CHUNK * P_DIM + p;
#pragma unroll 4
    for (int j = 0; j < CHUNK; ++j) {
        float2 b = bu[(size_t)j * P_DIM];
        float nxr = lr * xr - li * xi + b.x;
        float nxi = lr * xi + li * xr + b.y;
        xr = nxr; xi = nxi;
    }
    ((float2*)S)[(size_t)c * P_DIM + p] = make_float2(xr, xi);
}

__global__ __launch_bounds__(512) void k_scan_combine(const float* __restrict__ S,
                                                      const float* __restrict__ lambda_powN,
                                                      float* __restrict__ prefix) {
    int p = threadIdx.x;       // single block of 512
    float lr = lambda_powN[2 * p], li = lambda_powN[2 * p + 1];
    float xr = 0.f, xi = 0.f;
    const float2* Sp = (const float2*)S;
    float2* Pp = (float2*)prefix;
    for (int c0 = 0; c0 < NCHUNK; c0 += 8) {
        float2 sb[8];
#pragma unroll
        for (int j = 0; j < 8; ++j) sb[j] = Sp[(size_t)(c0 + j) * P_DIM + p];
#pragma unroll
        for (int j = 0; j < 8; ++j) {
            Pp[(size_t)(c0 + j) * P_DIM + p] = make_float2(xr, xi);
            float nxr = lr * xr - li * xi + sb[j].x;
            float nxi = lr * xi + li * xr + sb[j].y;
            xr = nxr; xi = nxi;
        }
    }
}

__global__ __launch_bounds__(256) void k_scan_apply(float* __restrict__ Bu,   // in-place -> xs
                                                    const float* __restrict__ lambda_bar,
                                                    const float* __restrict__ prefix) {
    int gid = blockIdx.x * blockDim.x + threadIdx.x;
    int c = gid >> 9, p = gid & 511;
    float lr = lambda_bar[2 * p], li = lambda_bar[2 * p + 1];
    float2 x0 = ((const float2*)prefix)[(size_t)c * P_DIM + p];
    float xr = x0.x, xi = x0.y;
    float2* bu = (float2*)Bu + (size_t)c * CHUNK * P_DIM + p;
#pragma unroll 4
    for (int j = 0; j < CHUNK; ++j) {
        float2 b = bu[(size_t)j * P_DIM];
        float nxr = lr * xr - li * xi + b.x;
        float nxi = lr * xi + li * xr + b.y;
        xr = nxr; xi = nxi;
        bu[(size_t)j * P_DIM] = make_float2(xr, xi);
    }
}

// ---------------------------------------------------------------------------
extern "C" void kernel_launch(void* const* d_in, const int* in_sizes, int n_in,
                              void* d_out, int out_size, void* d_ws, size_t ws_size,
                              hipStream_t stream) {
    const float* u        = (const float*)d_in[0];
    const float* Lre      = (const float*)d_in[1];
    const float* Lim      = (const float*)d_in[2];
    const float* Bin      = (const float*)d_in[3];
    const float* Cin      = (const float*)d_in[4];
    const float* Dv       = (const float*)d_in[5];
    const float* log_step = (const float*)d_in[6];
    float* y = (float*)d_out;

    char* w = (char*)d_ws;
    size_t off = 0;
    short* Bcat = (short*)(w + off); off += (size_t)2 * P_DIM * H_DIM * 2;   // 1 MB
    short* Ccat = (short*)(w + off); off += (size_t)2 * P_DIM * H_DIM * 2;   // 1 MB
    float* Bu   = (float*)(w + off); off += (size_t)L_DIM * 2 * P_DIM * 4;   // 32 MB (xs in-place)
    float* lamb = (float*)(w + off); off += 2 * P_DIM * 4;
    float* lamN = (float*)(w + off); off += 2 * P_DIM * 4;
    float* S    = (float*)(w + off); off += (size_t)NCHUNK * 2 * P_DIM * 4;  // 512 KB
    float* pref = (float*)(w + off); off += (size_t)NCHUNK * 2 * P_DIM * 4;  // 512 KB

    k_discretize<<<P_DIM, 256, 0, stream>>>(Lre, Lim, Bin, log_step, Bcat, lamb, lamN);
    k_build_ccat<<<(H_DIM * P_DIM + 255) / 256, 256, 0, stream>>>(Cin, Ccat);
    // GEMM1: Bu[L][2P] = u[L][H] * Bcat[2P][H]^T
    k_gemm_f32a_bf16b<false><<<dim3((2 * P_DIM) / 128, L_DIM / 128), 256, 0, stream>>>(
        u, Bcat, Bu, L_DIM, 2 * P_DIM, H_DIM, nullptr, nullptr);
    // Scan
    k_scan_summary<<<(NCHUNK * P_DIM) / 256, 256, 0, stream>>>(Bu, lamb, S);
    k_scan_combine<<<1, 512, 0, stream>>>(S, lamN, pref);
    k_scan_apply<<<(NCHUNK * P_DIM) / 256, 256, 0, stream>>>(Bu, lamb, pref);
    // GEMM2: y[L][H] = xs[L][2P] * Ccat[H][2P]^T + D*u
    k_gemm_f32a_bf16b<true><<<dim3(H_DIM / 128, L_DIM / 128), 256, 0, stream>>>(
        Bu, Ccat, y, L_DIM, H_DIM, 2 * P_DIM, Dv, u);
}

// Round 3
// 96.092 us; speedup vs baseline: 4.0264x; 1.2206x over previous
//
#include <hip/hip_runtime.h>
#include <hip/hip_bf16.h>

#define L_DIM 8192
#define H_DIM 512
#define P_DIM 512
#define CHUNK 64
#define NCHUNK (L_DIM / CHUNK)   // 128

typedef __attribute__((ext_vector_type(8))) short bf16x8;
typedef __attribute__((ext_vector_type(4))) float f32x4;

__device__ inline short f2bf(float x) {
    union { float f; unsigned u; } v; v.f = x;
    unsigned r = v.u + 0x7fffu + ((v.u >> 16) & 1u);
    return (short)(r >> 16);
}

__device__ inline void gload_lds16(const void* g, void* l) {
    __builtin_amdgcn_global_load_lds(
        (const __attribute__((address_space(1))) unsigned int*)g,
        (__attribute__((address_space(3))) unsigned int*)l, 16, 0, 0);
}

// ---------------------------------------------------------------------------
// K0: discretization -> Bcat (bf16), lambda_bar, lambda_powN
// ---------------------------------------------------------------------------
__global__ void k_discretize(const float* __restrict__ Lre, const float* __restrict__ Lim,
                             const float* __restrict__ Bin, const float* __restrict__ log_step,
                             short* __restrict__ Bcat, float* __restrict__ lambda_bar,
                             float* __restrict__ lambda_powN) {
    int p = blockIdx.x;
    float lr = Lre[p], li = Lim[p];
    float dt = expf(log_step[p]);
    float ar = lr * dt, ai = li * dt;
    float er = expf(ar);
    float lbr = er * cosf(ai);
    float lbi = er * sinf(ai);
    float nr = lbr - 1.0f, ni = lbi;
    float den = lr * lr + li * li;
    float fr = (nr * lr + ni * li) / den;
    float fi = (ni * lr - nr * li) / den;
    if (threadIdx.x == 0) {
        lambda_bar[2 * p] = lbr;
        lambda_bar[2 * p + 1] = lbi;
        float eN = expf(ar * (float)CHUNK);
        lambda_powN[2 * p] = eN * cosf(ai * (float)CHUNK);
        lambda_powN[2 * p + 1] = eN * sinf(ai * (float)CHUNK);
    }
    for (int h = threadIdx.x; h < H_DIM; h += blockDim.x) {
        float br = Bin[((size_t)p * H_DIM + h) * 2 + 0];
        float bi = Bin[((size_t)p * H_DIM + h) * 2 + 1];
        float Br = fr * br - fi * bi;
        float Bi = fr * bi + fi * br;
        Bcat[(size_t)(2 * p) * H_DIM + h] = f2bf(Br);
        Bcat[(size_t)(2 * p + 1) * H_DIM + h] = f2bf(Bi);
    }
}

// Ccat[h][2p] = C_re[h][p], Ccat[h][2p+1] = -C_im[h][p]   (bf16)
__global__ void k_build_ccat(const float* __restrict__ Cin, short* __restrict__ Ccat) {
    int idx = blockIdx.x * blockDim.x + threadIdx.x;
    if (idx >= H_DIM * P_DIM) return;
    int h = idx / P_DIM, p = idx % P_DIM;
    float cr = Cin[(size_t)idx * 2 + 0];
    float ci = Cin[(size_t)idx * 2 + 1];
    Ccat[(size_t)h * (2 * P_DIM) + 2 * p + 0] = f2bf(cr);
    Ccat[(size_t)h * (2 * P_DIM) + 2 * p + 1] = f2bf(-ci);
}

// ---------------------------------------------------------------------------
// 2-phase double-buffered MFMA GEMM: Cout[M][N] = A[M][K] * B[N][K]^T
//  ABF16=1: A is bf16, staged via global_load_lds (1 barrier/K-step)
//  ABF16=0: A is fp32, reg-staged + convert + ds_write (2 barriers/K-step,
//           global loads still overlapped with MFMA)
//  EPI: Cout += Dv[n] * U[m][n]
// 128x128 tile, BK=32, 4 waves, 16x16x32 bf16 MFMA, 4x4 frags/wave.
// 1-D grid with bijective XCD swizzle (requires nwg % 8 == 0).
// ---------------------------------------------------------------------------
template<bool ABF16, bool EPI>
__global__ __launch_bounds__(256) void k_gemm(
        const void* __restrict__ Avoid, const short* __restrict__ B,
        float* __restrict__ Cout, int M, int N, int K, int nwgn,
        const float* __restrict__ Dv, const float* __restrict__ U) {
    __shared__ short As[2][128 * 32];
    __shared__ short Bs[2][128 * 32];
    const int tid = threadIdx.x;
    const int lane = tid & 63;
    const int wid = tid >> 6;
    const int wr = wid >> 1, wc = wid & 1;

    // XCD-aware bijective swizzle
    const int nwg = gridDim.x;
    const int orig = blockIdx.x;
    const int id = (orig & 7) * (nwg >> 3) + (orig >> 3);
    const int bm = (id / nwgn) * 128;
    const int bn = (id % nwgn) * 128;

    // staging geometry: 8KB bf16 tile (128 rows x 64B), 2x16B per thread
    const int sbyte = wid * 2048 + lane * 16;
    const int srow = sbyte >> 6;
    const int scol = sbyte & 63;

    const float* Af = (const float*)Avoid;
    const short* Ab = (const short*)Avoid;

    f32x4 acc[4][4] = {};
    const int arow = wr * 64 + (lane & 15);
    const int brow = wc * 64 + (lane & 15);
    const int kgrp = (lane >> 4) * 8;

    float4 areg[4];

    auto stageB = [&](int buf, int kk) {
        const char* s0 = (const char*)B + ((size_t)(bn + srow) * K + kk) * 2 + scol;
        gload_lds16(s0, (char*)&Bs[buf][0] + sbyte);
        const char* s1 = (const char*)B + ((size_t)(bn + srow + 16) * K + kk) * 2 + scol;
        gload_lds16(s1, (char*)&Bs[buf][0] + sbyte + 1024);
    };
    auto stageAg = [&](int buf, int kk) {
        const char* s0 = (const char*)Ab + ((size_t)(bm + srow) * K + kk) * 2 + scol;
        gload_lds16(s0, (char*)&As[buf][0] + sbyte);
        const char* s1 = (const char*)Ab + ((size_t)(bm + srow + 16) * K + kk) * 2 + scol;
        gload_lds16(s1, (char*)&As[buf][0] + sbyte + 1024);
    };
    auto loadA = [&](int kk) {
#pragma unroll
        for (int q = 0; q < 4; ++q) {
            int f = q * 256 + tid;
            int row = f >> 3, c4 = f & 7;
            areg[q] = *(const float4*)(Af + (size_t)(bm + row) * K + kk + c4 * 4);
        }
    };
    auto writeA = [&](int buf) {
#pragma unroll
        for (int q = 0; q < 4; ++q) {
            int f = q * 256 + tid;
            int row = f >> 3, c4 = f & 7;
            short4 sv = make_short4(f2bf(areg[q].x), f2bf(areg[q].y),
                                    f2bf(areg[q].z), f2bf(areg[q].w));
            *(short4*)&As[buf][row * 32 + c4 * 4] = sv;
        }
    };

    // prologue: stage tile 0
    if (ABF16) stageAg(0, 0); else loadA(0);
    stageB(0, 0);
    if (!ABF16) writeA(0);
    __syncthreads();

    int cur = 0;
    const int nt = K >> 5;
    for (int t = 0; t < nt; ++t) {
        const bool nx = (t + 1 < nt);
        if (nx) {
            if (ABF16) stageAg(cur ^ 1, (t + 1) * 32); else loadA((t + 1) * 32);
            stageB(cur ^ 1, (t + 1) * 32);
        }
        bf16x8 af[4], bfr[4];
#pragma unroll
        for (int m = 0; m < 4; ++m) af[m] = *(const bf16x8*)&As[cur][(arow + m * 16) * 32 + kgrp];
#pragma unroll
        for (int n = 0; n < 4; ++n) bfr[n] = *(const bf16x8*)&Bs[cur][(brow + n * 16) * 32 + kgrp];
#pragma unroll
        for (int m = 0; m < 4; ++m)
#pragma unroll
            for (int n = 0; n < 4; ++n)
                acc[m][n] = __builtin_amdgcn_mfma_f32_16x16x32_bf16(af[m], bfr[n], acc[m][n], 0, 0, 0);
        __syncthreads();
        if (nx && !ABF16) { writeA(cur ^ 1); __syncthreads(); }
        cur ^= 1;
    }

    const int fq = lane >> 4, fr = lane & 15;
#pragma unroll
    for (int m = 0; m < 4; ++m) {
#pragma unroll
        for (int n = 0; n < 4; ++n) {
            int col = bn + wc * 64 + n * 16 + fr;
            int row0 = bm + wr * 64 + m * 16 + fq * 4;
#pragma unroll
            for (int j = 0; j < 4; ++j) {
                int row = row0 + j;
                float v = acc[m][n][j];
                if (EPI) v += Dv[col] * U[(size_t)row * N + col];
                Cout[(size_t)row * N + col] = v;
            }
        }
    }
}

// ---------------------------------------------------------------------------
// Scan kernels. Bu viewed as float2[L][P].
// ---------------------------------------------------------------------------
__global__ __launch_bounds__(256) void k_scan_summary(const float* __restrict__ Bu,
                                                      const float* __restrict__ lambda_bar,
                                                      float* __restrict__ S) {
    int gid = blockIdx.x * blockDim.x + threadIdx.x;
    int c = gid >> 9, p = gid & 511;
    float lr = lambda_bar[2 * p], li = lambda_bar[2 * p + 1];
    float xr = 0.f, xi = 0.f;
    const float2* bu = (const float2*)Bu + (size_t)c * CHUNK * P_DIM + p;
#pragma unroll 4
    for (int j = 0; j < CHUNK; ++j) {
        float2 b = bu[(size_t)j * P_DIM];
        float nxr = lr * xr - li * xi + b.x;
        float nxi = lr * xi + li * xr + b.y;
        xr = nxr; xi = nxi;
    }
    ((float2*)S)[(size_t)c * P_DIM + p] = make_float2(xr, xi);
}

__global__ __launch_bounds__(512) void k_scan_combine(const float* __restrict__ S,
                                                      const float* __restrict__ lambda_powN,
                                                      float* __restrict__ prefix) {
    int p = threadIdx.x;
    float lr = lambda_powN[2 * p], li = lambda_powN[2 * p + 1];
    float xr = 0.f, xi = 0.f;
    const float2* Sp = (const float2*)S;
    float2* Pp = (float2*)prefix;
    for (int c0 = 0; c0 < NCHUNK; c0 += 8) {
        float2 sb[8];
#pragma unroll
        for (int j = 0; j < 8; ++j) sb[j] = Sp[(size_t)(c0 + j) * P_DIM + p];
#pragma unroll
        for (int j = 0; j < 8; ++j) {
            Pp[(size_t)(c0 + j) * P_DIM + p] = make_float2(xr, xi);
            float nxr = lr * xr - li * xi + sb[j].x;
            float nxi = lr * xi + li * xr + sb[j].y;
            xr = nxr; xi = nxi;
        }
    }
}

// BF=1: write packed bf16 (re|im<<16) into XsB (Bu untouched)
// BF=0: write fp32 in place into XsF (= Bu)
template<bool BF>
__global__ __launch_bounds__(256) void k_scan_apply(const float* __restrict__ Bu,
                                                    float* __restrict__ XsF,
                                                    unsigned* __restrict__ XsB,
                                                    const float* __restrict__ lambda_bar,
                                                    const float* __restrict__ prefix) {
    int gid = blockIdx.x * blockDim.x + threadIdx.x;
    int c = gid >> 9, p = gid & 511;
    float lr = lambda_bar[2 * p], li = lambda_bar[2 * p + 1];
    float2 x0 = ((const float2*)prefix)[(size_t)c * P_DIM + p];
    float xr = x0.x, xi = x0.y;
    const float2* bu = (const float2*)Bu + (size_t)c * CHUNK * P_DIM + p;
#pragma unroll 4
    for (int j = 0; j < CHUNK; ++j) {
        float2 b = bu[(size_t)j * P_DIM];
        float nxr = lr * xr - li * xi + b.x;
        float nxi = lr * xi + li * xr + b.y;
        xr = nxr; xi = nxi;
        size_t l = (size_t)c * CHUNK + j;
        if (BF) {
            unsigned pk = (unsigned)(unsigned short)f2bf(xr)
                        | ((unsigned)(unsigned short)f2bf(xi) << 16);
            XsB[l * P_DIM + p] = pk;
        } else {
            ((float2*)XsF)[l * P_DIM + p] = make_float2(xr, xi);
        }
    }
}

// ---------------------------------------------------------------------------
extern "C" void kernel_launch(void* const* d_in, const int* in_sizes, int n_in,
                              void* d_out, int out_size, void* d_ws, size_t ws_size,
                              hipStream_t stream) {
    const float* u        = (const float*)d_in[0];
    const float* Lre      = (const float*)d_in[1];
    const float* Lim      = (const float*)d_in[2];
    const float* Bin      = (const float*)d_in[3];
    const float* Cin      = (const float*)d_in[4];
    const float* Dv       = (const float*)d_in[5];
    const float* log_step = (const float*)d_in[6];
    float* y = (float*)d_out;

    char* w = (char*)d_ws;
    size_t off = 0;
    short* Bcat = (short*)(w + off); off += (size_t)2 * P_DIM * H_DIM * 2;   // 1 MB
    short* Ccat = (short*)(w + off); off += (size_t)2 * P_DIM * H_DIM * 2;   // 1 MB
    float* lamb = (float*)(w + off); off += 2 * P_DIM * 4;
    float* lamN = (float*)(w + off); off += 2 * P_DIM * 4;
    float* S    = (float*)(w + off); off += (size_t)NCHUNK * 2 * P_DIM * 4;  // 512 KB
    float* pref = (float*)(w + off); off += (size_t)NCHUNK * 2 * P_DIM * 4;  // 512 KB
    float* Bu   = (float*)(w + off); off += (size_t)L_DIM * 2 * P_DIM * 4;   // 32 MB
    unsigned* XsB = (unsigned*)(w + off);
    size_t need = off + (size_t)L_DIM * P_DIM * 4;                           // +16 MB
    const bool big = (ws_size >= need);

    k_discretize<<<P_DIM, 256, 0, stream>>>(Lre, Lim, Bin, log_step, Bcat, lamb, lamN);
    k_build_ccat<<<(H_DIM * P_DIM + 255) / 256, 256, 0, stream>>>(Cin, Ccat);

    // GEMM1: Bu[L][2P] = u[L][H](fp32) * Bcat[2P][H]^T
    k_gemm<false, false><<<(L_DIM / 128) * ((2 * P_DIM) / 128), 256, 0, stream>>>(
        u, Bcat, Bu, L_DIM, 2 * P_DIM, H_DIM, (2 * P_DIM) / 128, nullptr, nullptr);

    // Scan
    k_scan_summary<<<(NCHUNK * P_DIM) / 256, 256, 0, stream>>>(Bu, lamb, S);
    k_scan_combine<<<1, 512, 0, stream>>>(S, lamN, pref);
    if (big) {
        k_scan_apply<true><<<(NCHUNK * P_DIM) / 256, 256, 0, stream>>>(Bu, nullptr, XsB, lamb, pref);
        // GEMM2: y[L][H] = xs_bf16[L][2P] * Ccat[H][2P]^T + D*u
        k_gemm<true, true><<<(L_DIM / 128) * (H_DIM / 128), 256, 0, stream>>>(
            (const void*)XsB, Ccat, y, L_DIM, H_DIM, 2 * P_DIM, H_DIM / 128, Dv, u);
    } else {
        k_scan_apply<false><<<(NCHUNK * P_DIM) / 256, 256, 0, stream>>>(Bu, Bu, nullptr, lamb, pref);
        k_gemm<false, true><<<(L_DIM / 128) * (H_DIM / 128), 256, 0, stream>>>(
            (const void*)Bu, Ccat, y, L_DIM, H_DIM, 2 * P_DIM, H_DIM / 128, Dv, u);
    }
}

// Round 4
// 84.183 us; speedup vs baseline: 4.5960x; 1.1415x over previous
//
#include <hip/hip_runtime.h>
#include <hip/hip_bf16.h>

#define L_DIM 8192
#define H_DIM 512
#define P_DIM 512
#define CHUNK 32
#define NCHUNK (L_DIM / CHUNK)   // 256

typedef __attribute__((ext_vector_type(8))) short bf16x8;
typedef __attribute__((ext_vector_type(4))) float f32x4;

__device__ inline short f2bf(float x) {
    union { float f; unsigned u; } v; v.f = x;
    unsigned r = v.u + 0x7fffu + ((v.u >> 16) & 1u);
    return (short)(r >> 16);
}

__device__ inline void gload_lds16(const void* g, void* l) {
    __builtin_amdgcn_global_load_lds(
        (const __attribute__((address_space(1))) unsigned int*)g,
        (__attribute__((address_space(3))) unsigned int*)l, 16, 0, 0);
}

// ---------------------------------------------------------------------------
// Fused prep:
//   blocks [0,512):        discretize -> Bcat bf16, lambda_bar, lambda_powN
//   blocks [512,1536):     Ccat bf16
//   blocks [1536,3584):    u fp32 -> u_bf bf16
// ---------------------------------------------------------------------------
__global__ __launch_bounds__(256) void k_prep(
        const float* __restrict__ Lre, const float* __restrict__ Lim,
        const float* __restrict__ Bin, const float* __restrict__ log_step,
        const float* __restrict__ Cin, const float* __restrict__ u,
        short* __restrict__ Bcat, short* __restrict__ Ccat,
        short* __restrict__ u_bf,
        float* __restrict__ lambda_bar, float* __restrict__ lambda_powN) {
    const int blk = blockIdx.x;
    const int tid = threadIdx.x;
    if (blk < P_DIM) {
        int p = blk;
        float lr = Lre[p], li = Lim[p];
        float dt = expf(log_step[p]);
        float ar = lr * dt, ai = li * dt;
        float er = expf(ar);
        float lbr = er * cosf(ai);
        float lbi = er * sinf(ai);
        float nr = lbr - 1.0f, ni = lbi;
        float den = lr * lr + li * li;
        float fr = (nr * lr + ni * li) / den;
        float fi = (ni * lr - nr * li) / den;
        if (tid == 0) {
            lambda_bar[2 * p] = lbr;
            lambda_bar[2 * p + 1] = lbi;
            float eN = expf(ar * (float)CHUNK);
            lambda_powN[2 * p] = eN * cosf(ai * (float)CHUNK);
            lambda_powN[2 * p + 1] = eN * sinf(ai * (float)CHUNK);
        }
        for (int h = tid; h < H_DIM; h += 256) {
            float br = Bin[((size_t)p * H_DIM + h) * 2 + 0];
            float bi = Bin[((size_t)p * H_DIM + h) * 2 + 1];
            Bcat[(size_t)(2 * p) * H_DIM + h] = f2bf(fr * br - fi * bi);
            Bcat[(size_t)(2 * p + 1) * H_DIM + h] = f2bf(fr * bi + fi * br);
        }
    } else if (blk < P_DIM + 1024) {
        int idx = (blk - P_DIM) * 256 + tid;           // over H*P
        int h = idx >> 9, p = idx & 511;
        float cr = Cin[(size_t)idx * 2 + 0];
        float ci = Cin[(size_t)idx * 2 + 1];
        Ccat[(size_t)h * (2 * P_DIM) + 2 * p + 0] = f2bf(cr);
        Ccat[(size_t)h * (2 * P_DIM) + 2 * p + 1] = f2bf(-ci);
    } else {
        int i = (blk - P_DIM - 1024) * 256 + tid;      // over (L*H)/8
        const float4* uf = (const float4*)u;
        float4 a0 = uf[(size_t)i * 2];
        float4 a1 = uf[(size_t)i * 2 + 1];
        bf16x8 sv;
        sv[0] = f2bf(a0.x); sv[1] = f2bf(a0.y); sv[2] = f2bf(a0.z); sv[3] = f2bf(a0.w);
        sv[4] = f2bf(a1.x); sv[5] = f2bf(a1.y); sv[6] = f2bf(a1.z); sv[7] = f2bf(a1.w);
        *(bf16x8*)&u_bf[(size_t)i * 8] = sv;
    }
}

// ---------------------------------------------------------------------------
// 2-phase double-buffered MFMA GEMM: Cout[M][N] = A[M][K] * B[N][K]^T
//  ABF16=1: A bf16, pure global_load_lds (1 barrier/K-step)
//  ABF16=0: A fp32, reg-staged + convert + ds_write (fallback path)
//  EPI: Cout += Dv[n] * U[m][n]
// 128x128 tile, BK=32, 4 waves, 16x16x32 bf16 MFMA, 4x4 frags/wave.
// 1-D grid, bijective XCD swizzle (nwg % 8 == 0).
// ---------------------------------------------------------------------------
template<bool ABF16, bool EPI>
__global__ __launch_bounds__(256) void k_gemm(
        const void* __restrict__ Avoid, const short* __restrict__ B,
        float* __restrict__ Cout, int M, int N, int K, int nwgn,
        const float* __restrict__ Dv, const float* __restrict__ U) {
    __shared__ short As[2][128 * 32];
    __shared__ short Bs[2][128 * 32];
    const int tid = threadIdx.x;
    const int lane = tid & 63;
    const int wid = tid >> 6;
    const int wr = wid >> 1, wc = wid & 1;

    const int nwg = gridDim.x;
    const int orig = blockIdx.x;
    const int id = (orig & 7) * (nwg >> 3) + (orig >> 3);
    const int bm = (id / nwgn) * 128;
    const int bn = (id % nwgn) * 128;

    const int sbyte = wid * 2048 + lane * 16;
    const int srow = sbyte >> 6;
    const int scol = sbyte & 63;

    const float* Af = (const float*)Avoid;
    const short* Ab = (const short*)Avoid;

    f32x4 acc[4][4] = {};
    const int arow = wr * 64 + (lane & 15);
    const int brow = wc * 64 + (lane & 15);
    const int kgrp = (lane >> 4) * 8;

    float4 areg[4];

    auto stageB = [&](int buf, int kk) {
        const char* s0 = (const char*)B + ((size_t)(bn + srow) * K + kk) * 2 + scol;
        gload_lds16(s0, (char*)&Bs[buf][0] + sbyte);
        const char* s1 = (const char*)B + ((size_t)(bn + srow + 16) * K + kk) * 2 + scol;
        gload_lds16(s1, (char*)&Bs[buf][0] + sbyte + 1024);
    };
    auto stageAg = [&](int buf, int kk) {
        const char* s0 = (const char*)Ab + ((size_t)(bm + srow) * K + kk) * 2 + scol;
        gload_lds16(s0, (char*)&As[buf][0] + sbyte);
        const char* s1 = (const char*)Ab + ((size_t)(bm + srow + 16) * K + kk) * 2 + scol;
        gload_lds16(s1, (char*)&As[buf][0] + sbyte + 1024);
    };
    auto loadA = [&](int kk) {
#pragma unroll
        for (int q = 0; q < 4; ++q) {
            int f = q * 256 + tid;
            int row = f >> 3, c4 = f & 7;
            areg[q] = *(const float4*)(Af + (size_t)(bm + row) * K + kk + c4 * 4);
        }
    };
    auto writeA = [&](int buf) {
#pragma unroll
        for (int q = 0; q < 4; ++q) {
            int f = q * 256 + tid;
            int row = f >> 3, c4 = f & 7;
            short4 sv = make_short4(f2bf(areg[q].x), f2bf(areg[q].y),
                                    f2bf(areg[q].z), f2bf(areg[q].w));
            *(short4*)&As[buf][row * 32 + c4 * 4] = sv;
        }
    };

    if (ABF16) stageAg(0, 0); else loadA(0);
    stageB(0, 0);
    if (!ABF16) writeA(0);
    __syncthreads();

    int cur = 0;
    const int nt = K >> 5;
    for (int t = 0; t < nt; ++t) {
        const bool nx = (t + 1 < nt);
        if (nx) {
            if (ABF16) stageAg(cur ^ 1, (t + 1) * 32); else loadA((t + 1) * 32);
            stageB(cur ^ 1, (t + 1) * 32);
        }
        bf16x8 af[4], bfr[4];
#pragma unroll
        for (int m = 0; m < 4; ++m) af[m] = *(const bf16x8*)&As[cur][(arow + m * 16) * 32 + kgrp];
#pragma unroll
        for (int n = 0; n < 4; ++n) bfr[n] = *(const bf16x8*)&Bs[cur][(brow + n * 16) * 32 + kgrp];
#pragma unroll
        for (int m = 0; m < 4; ++m)
#pragma unroll
            for (int n = 0; n < 4; ++n)
                acc[m][n] = __builtin_amdgcn_mfma_f32_16x16x32_bf16(af[m], bfr[n], acc[m][n], 0, 0, 0);
        __syncthreads();
        if (nx && !ABF16) { writeA(cur ^ 1); __syncthreads(); }
        cur ^= 1;
    }

    const int fq = lane >> 4, fr = lane & 15;
#pragma unroll
    for (int m = 0; m < 4; ++m) {
#pragma unroll
        for (int n = 0; n < 4; ++n) {
            int col = bn + wc * 64 + n * 16 + fr;
            int row0 = bm + wr * 64 + m * 16 + fq * 4;
#pragma unroll
            for (int j = 0; j < 4; ++j) {
                int row = row0 + j;
                float v = acc[m][n][j];
                if (EPI) v += Dv[col] * U[(size_t)row * N + col];
                Cout[(size_t)row * N + col] = v;
            }
        }
    }
}

// ---------------------------------------------------------------------------
// Scan. Bu viewed as float2[L][P]. CHUNK=32, NCHUNK=256.
// ---------------------------------------------------------------------------
__global__ __launch_bounds__(256) void k_scan_summary(const float* __restrict__ Bu,
                                                      const float* __restrict__ lambda_bar,
                                                      float* __restrict__ S) {
    int gid = blockIdx.x * blockDim.x + threadIdx.x;   // NCHUNK*P threads
    int c = gid >> 9, p = gid & 511;
    float lr = lambda_bar[2 * p], li = lambda_bar[2 * p + 1];
    float xr = 0.f, xi = 0.f;
    const float2* bu = (const float2*)Bu + (size_t)c * CHUNK * P_DIM + p;
#pragma unroll 4
    for (int j = 0; j < CHUNK; ++j) {
        float2 b = bu[(size_t)j * P_DIM];
        float nxr = lr * xr - li * xi + b.x;
        float nxi = lr * xi + li * xr + b.y;
        xr = nxr; xi = nxi;
    }
    ((float2*)S)[(size_t)c * P_DIM + p] = make_float2(xr, xi);
}

// One block per chunk (512 threads = channels). Each block reconstructs its
// own prefix from S (batched lambda^N-weighted accumulation), then scans its
// chunk. BF=1: write packed bf16 to XsB. BF=0: write fp32 in place (XsF=Bu).
template<bool BF>
__global__ __launch_bounds__(512) void k_scan_apply(const float* __restrict__ Bu,
                                                    float* __restrict__ XsF,
                                                    unsigned* __restrict__ XsB,
                                                    const float* __restrict__ lambda_bar,
                                                    const float* __restrict__ lambda_powN,
                                                    const float* __restrict__ S) {
    const int c = blockIdx.x;
    const int p = threadIdx.x;
    const float lNr = lambda_powN[2 * p], lNi = lambda_powN[2 * p + 1];
    float xr = 0.f, xi = 0.f;
    const float2* Sp = (const float2*)S;
    int d = 0;
    while (d + 8 <= c) {
        float2 sb[8];
#pragma unroll
        for (int j = 0; j < 8; ++j) sb[j] = Sp[(size_t)(d + j) * P_DIM + p];
#pragma unroll
        for (int j = 0; j < 8; ++j) {
            float nxr = lNr * xr - lNi * xi + sb[j].x;
            float nxi = lNr * xi + lNi * xr + sb[j].y;
            xr = nxr; xi = nxi;
        }
        d += 8;
    }
    for (; d < c; ++d) {
        float2 s = Sp[(size_t)d * P_DIM + p];
        float nxr = lNr * xr - lNi * xi + s.x;
        float nxi = lNr * xi + lNi * xr + s.y;
        xr = nxr; xi = nxi;
    }
    const float lr = lambda_bar[2 * p], li = lambda_bar[2 * p + 1];
    const float2* bu = (const float2*)Bu + (size_t)c * CHUNK * P_DIM + p;
#pragma unroll 4
    for (int j = 0; j < CHUNK; ++j) {
        float2 b = bu[(size_t)j * P_DIM];
        float nxr = lr * xr - li * xi + b.x;
        float nxi = lr * xi + li * xr + b.y;
        xr = nxr; xi = nxi;
        size_t l = (size_t)c * CHUNK + j;
        if (BF) {
            unsigned pk = (unsigned)(unsigned short)f2bf(xr)
                        | ((unsigned)(unsigned short)f2bf(xi) << 16);
            XsB[l * P_DIM + p] = pk;
        } else {
            ((float2*)XsF)[l * P_DIM + p] = make_float2(xr, xi);
        }
    }
}

// ---------------------------------------------------------------------------
extern "C" void kernel_launch(void* const* d_in, const int* in_sizes, int n_in,
                              void* d_out, int out_size, void* d_ws, size_t ws_size,
                              hipStream_t stream) {
    const float* u        = (const float*)d_in[0];
    const float* Lre      = (const float*)d_in[1];
    const float* Lim      = (const float*)d_in[2];
    const float* Bin      = (const float*)d_in[3];
    const float* Cin      = (const float*)d_in[4];
    const float* Dv       = (const float*)d_in[5];
    const float* log_step = (const float*)d_in[6];
    float* y = (float*)d_out;

    char* w = (char*)d_ws;
    size_t off = 0;
    short* Bcat = (short*)(w + off); off += (size_t)2 * P_DIM * H_DIM * 2;   // 1 MB
    short* Ccat = (short*)(w + off); off += (size_t)2 * P_DIM * H_DIM * 2;   // 1 MB
    float* lamb = (float*)(w + off); off += 2 * P_DIM * 4;
    float* lamN = (float*)(w + off); off += 2 * P_DIM * 4;
    float* S    = (float*)(w + off); off += (size_t)NCHUNK * 2 * P_DIM * 4;  // 1 MB
    float* Bu   = (float*)(w + off); off += (size_t)L_DIM * 2 * P_DIM * 4;   // 32 MB
    unsigned* XsB = (unsigned*)(w + off);
    size_t off2 = off + (size_t)L_DIM * P_DIM * 4;                           // +16 MB
    short* u_bf = (short*)(w + off2);
    size_t need = off2 + (size_t)L_DIM * H_DIM * 2;                          // +8 MB
    const bool big = (ws_size >= need);

    if (big) {
        k_prep<<<P_DIM + 1024 + 2048, 256, 0, stream>>>(
            Lre, Lim, Bin, log_step, Cin, u, Bcat, Ccat, u_bf, lamb, lamN);
        // GEMM1: Bu[L][2P] = u_bf[L][H] * Bcat[2P][H]^T
        k_gemm<true, false><<<(L_DIM / 128) * ((2 * P_DIM) / 128), 256, 0, stream>>>(
            (const void*)u_bf, Bcat, Bu, L_DIM, 2 * P_DIM, H_DIM, (2 * P_DIM) / 128,
            nullptr, nullptr);
        k_scan_summary<<<(NCHUNK * P_DIM) / 256, 256, 0, stream>>>(Bu, lamb, S);
        k_scan_apply<true><<<NCHUNK, 512, 0, stream>>>(Bu, nullptr, XsB, lamb, lamN, S);
        // GEMM2: y[L][H] = xs_bf16[L][2P] * Ccat[H][2P]^T + D*u
        k_gemm<true, true><<<(L_DIM / 128) * (H_DIM / 128), 256, 0, stream>>>(
            (const void*)XsB, Ccat, y, L_DIM, H_DIM, 2 * P_DIM, H_DIM / 128, Dv, u);
    } else {
        k_prep<<<P_DIM + 1024, 256, 0, stream>>>(
            Lre, Lim, Bin, log_step, Cin, u, Bcat, Ccat, nullptr, lamb, lamN);
        k_gemm<false, false><<<(L_DIM / 128) * ((2 * P_DIM) / 128), 256, 0, stream>>>(
            (const void*)u, Bcat, Bu, L_DIM, 2 * P_DIM, H_DIM, (2 * P_DIM) / 128,
            nullptr, nullptr);
        k_scan_summary<<<(NCHUNK * P_DIM) / 256, 256, 0, stream>>>(Bu, lamb, S);
        k_scan_apply<false><<<NCHUNK, 512, 0, stream>>>(Bu, Bu, nullptr, lamb, lamN, S);
        k_gemm<false, true><<<(L_DIM / 128) * (H_DIM / 128), 256, 0, stream>>>(
            (const void*)Bu, Ccat, y, L_DIM, H_DIM, 2 * P_DIM, H_DIM / 128, Dv, u);
    }
}

// Round 5
// 81.613 us; speedup vs baseline: 4.7407x; 1.0315x over previous
//
#include <hip/hip_runtime.h>
#include <hip/hip_bf16.h>

#define L_DIM 8192
#define H_DIM 512
#define P_DIM 512
#define CHUNK 32
#define NCHUNK (L_DIM / CHUNK)   // 256

typedef __attribute__((ext_vector_type(8))) short bf16x8;
typedef __attribute__((ext_vector_type(4))) float f32x4;

__device__ inline short f2bf(float x) {
    union { float f; unsigned u; } v; v.f = x;
    unsigned r = v.u + 0x7fffu + ((v.u >> 16) & 1u);
    return (short)(r >> 16);
}
__device__ inline float bflo2f(unsigned w) {       // low 16 bits as bf16
    union { unsigned u; float f; } v; v.u = w << 16; return v.f;
}
__device__ inline float bfhi2f(unsigned w) {       // high 16 bits as bf16
    union { unsigned u; float f; } v; v.u = w & 0xffff0000u; return v.f;
}

__device__ inline void gload_lds16(const void* g, void* l) {
    __builtin_amdgcn_global_load_lds(
        (const __attribute__((address_space(1))) unsigned int*)g,
        (__attribute__((address_space(3))) unsigned int*)l, 16, 0, 0);
}

// ---------------------------------------------------------------------------
// Fused prep:
//   blocks [0,512):        discretize -> Bcat bf16, lambda_bar, lambda_powN
//   blocks [512,1536):     Ccat bf16
//   blocks [1536,3584):    u fp32 -> u_bf bf16
// ---------------------------------------------------------------------------
__global__ __launch_bounds__(256) void k_prep(
        const float* __restrict__ Lre, const float* __restrict__ Lim,
        const float* __restrict__ Bin, const float* __restrict__ log_step,
        const float* __restrict__ Cin, const float* __restrict__ u,
        short* __restrict__ Bcat, short* __restrict__ Ccat,
        short* __restrict__ u_bf,
        float* __restrict__ lambda_bar, float* __restrict__ lambda_powN) {
    const int blk = blockIdx.x;
    const int tid = threadIdx.x;
    if (blk < P_DIM) {
        int p = blk;
        float lr = Lre[p], li = Lim[p];
        float dt = expf(log_step[p]);
        float ar = lr * dt, ai = li * dt;
        float er = expf(ar);
        float lbr = er * cosf(ai);
        float lbi = er * sinf(ai);
        float nr = lbr - 1.0f, ni = lbi;
        float den = lr * lr + li * li;
        float fr = (nr * lr + ni * li) / den;
        float fi = (ni * lr - nr * li) / den;
        if (tid == 0) {
            lambda_bar[2 * p] = lbr;
            lambda_bar[2 * p + 1] = lbi;
            float eN = expf(ar * (float)CHUNK);
            lambda_powN[2 * p] = eN * cosf(ai * (float)CHUNK);
            lambda_powN[2 * p + 1] = eN * sinf(ai * (float)CHUNK);
        }
        for (int h = tid; h < H_DIM; h += 256) {
            float br = Bin[((size_t)p * H_DIM + h) * 2 + 0];
            float bi = Bin[((size_t)p * H_DIM + h) * 2 + 1];
            Bcat[(size_t)(2 * p) * H_DIM + h] = f2bf(fr * br - fi * bi);
            Bcat[(size_t)(2 * p + 1) * H_DIM + h] = f2bf(fr * bi + fi * br);
        }
    } else if (blk < P_DIM + 1024) {
        int idx = (blk - P_DIM) * 256 + tid;           // over H*P
        int h = idx >> 9, p = idx & 511;
        float cr = Cin[(size_t)idx * 2 + 0];
        float ci = Cin[(size_t)idx * 2 + 1];
        Ccat[(size_t)h * (2 * P_DIM) + 2 * p + 0] = f2bf(cr);
        Ccat[(size_t)h * (2 * P_DIM) + 2 * p + 1] = f2bf(-ci);
    } else {
        int i = (blk - P_DIM - 1024) * 256 + tid;      // over (L*H)/8
        const float4* uf = (const float4*)u;
        float4 a0 = uf[(size_t)i * 2];
        float4 a1 = uf[(size_t)i * 2 + 1];
        bf16x8 sv;
        sv[0] = f2bf(a0.x); sv[1] = f2bf(a0.y); sv[2] = f2bf(a0.z); sv[3] = f2bf(a0.w);
        sv[4] = f2bf(a1.x); sv[5] = f2bf(a1.y); sv[6] = f2bf(a1.z); sv[7] = f2bf(a1.w);
        *(bf16x8*)&u_bf[(size_t)i * 8] = sv;
    }
}

// ---------------------------------------------------------------------------
// 2-phase double-buffered MFMA GEMM: out[M][N] = A[M][K] * B[N][K]^T
//  A, B bf16; both staged via global_load_lds (1 barrier/K-step).
//  OBF16=1: store bf16 shorts (GEMM1 -> Bu packed). else fp32.
//  EPI: out += Dv[n] * bf2f(Ubf[m][n])  (GEMM2)
// 128x128 tile, BK=32, 4 waves, 16x16x32 bf16 MFMA, 4x4 frags/wave.
// 1-D grid, bijective XCD swizzle (nwg % 8 == 0).
// ---------------------------------------------------------------------------
template<bool OBF16, bool EPI>
__global__ __launch_bounds__(256) void k_gemm(
        const short* __restrict__ A, const short* __restrict__ B,
        void* __restrict__ Cout, int M, int N, int K, int nwgn,
        const float* __restrict__ Dv, const short* __restrict__ Ubf) {
    __shared__ short As[2][128 * 32];
    __shared__ short Bs[2][128 * 32];
    const int tid = threadIdx.x;
    const int lane = tid & 63;
    const int wid = tid >> 6;
    const int wr = wid >> 1, wc = wid & 1;

    const int nwg = gridDim.x;
    const int orig = blockIdx.x;
    const int id = (orig & 7) * (nwg >> 3) + (orig >> 3);
    const int bm = (id / nwgn) * 128;
    const int bn = (id % nwgn) * 128;

    const int sbyte = wid * 2048 + lane * 16;
    const int srow = sbyte >> 6;
    const int scol = sbyte & 63;

    f32x4 acc[4][4] = {};
    const int arow = wr * 64 + (lane & 15);
    const int brow = wc * 64 + (lane & 15);
    const int kgrp = (lane >> 4) * 8;

    auto stage = [&](int buf, int kk) {
        const char* a0 = (const char*)A + ((size_t)(bm + srow) * K + kk) * 2 + scol;
        gload_lds16(a0, (char*)&As[buf][0] + sbyte);
        const char* a1 = (const char*)A + ((size_t)(bm + srow + 16) * K + kk) * 2 + scol;
        gload_lds16(a1, (char*)&As[buf][0] + sbyte + 1024);
        const char* b0 = (const char*)B + ((size_t)(bn + srow) * K + kk) * 2 + scol;
        gload_lds16(b0, (char*)&Bs[buf][0] + sbyte);
        const char* b1 = (const char*)B + ((size_t)(bn + srow + 16) * K + kk) * 2 + scol;
        gload_lds16(b1, (char*)&Bs[buf][0] + sbyte + 1024);
    };

    stage(0, 0);
    __syncthreads();

    int cur = 0;
    const int nt = K >> 5;
    for (int t = 0; t < nt; ++t) {
        if (t + 1 < nt) stage(cur ^ 1, (t + 1) * 32);
        bf16x8 af[4], bfr[4];
#pragma unroll
        for (int m = 0; m < 4; ++m) af[m] = *(const bf16x8*)&As[cur][(arow + m * 16) * 32 + kgrp];
#pragma unroll
        for (int n = 0; n < 4; ++n) bfr[n] = *(const bf16x8*)&Bs[cur][(brow + n * 16) * 32 + kgrp];
#pragma unroll
        for (int m = 0; m < 4; ++m)
#pragma unroll
            for (int n = 0; n < 4; ++n)
                acc[m][n] = __builtin_amdgcn_mfma_f32_16x16x32_bf16(af[m], bfr[n], acc[m][n], 0, 0, 0);
        __syncthreads();
        cur ^= 1;
    }

    const int fq = lane >> 4, fr = lane & 15;
#pragma unroll
    for (int m = 0; m < 4; ++m) {
#pragma unroll
        for (int n = 0; n < 4; ++n) {
            int col = bn + wc * 64 + n * 16 + fr;
            int row0 = bm + wr * 64 + m * 16 + fq * 4;
#pragma unroll
            for (int j = 0; j < 4; ++j) {
                int row = row0 + j;
                float v = acc[m][n][j];
                if (OBF16) {
                    ((short*)Cout)[(size_t)row * N + col] = f2bf(v);
                } else {
                    if (EPI) {
                        union { unsigned u; float f; } ub;
                        ub.u = ((unsigned)(unsigned short)Ubf[(size_t)row * N + col]) << 16;
                        v += Dv[col] * ub.f;
                    }
                    ((float*)Cout)[(size_t)row * N + col] = v;
                }
            }
        }
    }
}

// ---------------------------------------------------------------------------
// Scan. Bu stored as packed bf16 (re = lo16 @ col 2p, im = hi16 @ col 2p+1).
// ---------------------------------------------------------------------------
__global__ __launch_bounds__(256) void k_scan_summary(const unsigned* __restrict__ Bu,
                                                      const float* __restrict__ lambda_bar,
                                                      float* __restrict__ S) {
    int gid = blockIdx.x * blockDim.x + threadIdx.x;   // NCHUNK*P threads
    int c = gid >> 9, p = gid & 511;
    float lr = lambda_bar[2 * p], li = lambda_bar[2 * p + 1];
    float xr = 0.f, xi = 0.f;
    const unsigned* bu = Bu + (size_t)c * CHUNK * P_DIM + p;
#pragma unroll 4
    for (int j = 0; j < CHUNK; ++j) {
        unsigned w = bu[(size_t)j * P_DIM];
        float br = bflo2f(w), bi = bfhi2f(w);
        float nxr = lr * xr - li * xi + br;
        float nxi = lr * xi + li * xr + bi;
        xr = nxr; xi = nxi;
    }
    ((float2*)S)[(size_t)c * P_DIM + p] = make_float2(xr, xi);
}

// One block per chunk (512 threads = channels). Reconstructs its prefix from
// S via lambda^N-weighted accumulation, scans its chunk, writes packed bf16.
__global__ __launch_bounds__(512) void k_scan_apply(const unsigned* __restrict__ Bu,
                                                    unsigned* __restrict__ XsB,
                                                    const float* __restrict__ lambda_bar,
                                                    const float* __restrict__ lambda_powN,
                                                    const float* __restrict__ S) {
    const int c = blockIdx.x;
    const int p = threadIdx.x;
    const float lNr = lambda_powN[2 * p], lNi = lambda_powN[2 * p + 1];
    float xr = 0.f, xi = 0.f;
    const float2* Sp = (const float2*)S;
    int d = 0;
    while (d + 8 <= c) {
        float2 sb[8];
#pragma unroll
        for (int j = 0; j < 8; ++j) sb[j] = Sp[(size_t)(d + j) * P_DIM + p];
#pragma unroll
        for (int j = 0; j < 8; ++j) {
            float nxr = lNr * xr - lNi * xi + sb[j].x;
            float nxi = lNr * xi + lNi * xr + sb[j].y;
            xr = nxr; xi = nxi;
        }
        d += 8;
    }
    for (; d < c; ++d) {
        float2 s = Sp[(size_t)d * P_DIM + p];
        float nxr = lNr * xr - lNi * xi + s.x;
        float nxi = lNr * xi + lNi * xr + s.y;
        xr = nxr; xi = nxi;
    }
    const float lr = lambda_bar[2 * p], li = lambda_bar[2 * p + 1];
    const unsigned* bu = Bu + (size_t)c * CHUNK * P_DIM + p;
#pragma unroll 4
    for (int j = 0; j < CHUNK; ++j) {
        unsigned w = bu[(size_t)j * P_DIM];
        float br = bflo2f(w), bi = bfhi2f(w);
        float nxr = lr * xr - li * xi + br;
        float nxi = lr * xi + li * xr + bi;
        xr = nxr; xi = nxi;
        unsigned pk = (unsigned)(unsigned short)f2bf(xr)
                    | ((unsigned)(unsigned short)f2bf(xi) << 16);
        XsB[((size_t)c * CHUNK + j) * P_DIM + p] = pk;
    }
}

// ---------------------------------------------------------------------------
extern "C" void kernel_launch(void* const* d_in, const int* in_sizes, int n_in,
                              void* d_out, int out_size, void* d_ws, size_t ws_size,
                              hipStream_t stream) {
    const float* u        = (const float*)d_in[0];
    const float* Lre      = (const float*)d_in[1];
    const float* Lim      = (const float*)d_in[2];
    const float* Bin      = (const float*)d_in[3];
    const float* Cin      = (const float*)d_in[4];
    const float* Dv       = (const float*)d_in[5];
    const float* log_step = (const float*)d_in[6];
    float* y = (float*)d_out;

    char* w = (char*)d_ws;
    size_t off = 0;
    short* Bcat = (short*)(w + off); off += (size_t)2 * P_DIM * H_DIM * 2;   // 1 MB
    short* Ccat = (short*)(w + off); off += (size_t)2 * P_DIM * H_DIM * 2;   // 1 MB
    float* lamb = (float*)(w + off); off += 2 * P_DIM * 4;
    float* lamN = (float*)(w + off); off += 2 * P_DIM * 4;
    float* S    = (float*)(w + off); off += (size_t)NCHUNK * 2 * P_DIM * 4;  // 1 MB
    unsigned* Bu  = (unsigned*)(w + off); off += (size_t)L_DIM * P_DIM * 4;  // 16 MB (packed bf16)
    unsigned* XsB = (unsigned*)(w + off); off += (size_t)L_DIM * P_DIM * 4;  // 16 MB (packed bf16)
    short* u_bf   = (short*)(w + off);   off += (size_t)L_DIM * H_DIM * 2;   // 8 MB

    // prep: discretize + Ccat + u->bf16
    k_prep<<<P_DIM + 1024 + 2048, 256, 0, stream>>>(
        Lre, Lim, Bin, log_step, Cin, u, Bcat, Ccat, u_bf, lamb, lamN);
    // GEMM1: Bu[L][2P](bf16 packed) = u_bf[L][H] * Bcat[2P][H]^T
    k_gemm<true, false><<<(L_DIM / 128) * ((2 * P_DIM) / 128), 256, 0, stream>>>(
        u_bf, Bcat, (void*)Bu, L_DIM, 2 * P_DIM, H_DIM, (2 * P_DIM) / 128,
        nullptr, nullptr);
    // Scan
    k_scan_summary<<<(NCHUNK * P_DIM) / 256, 256, 0, stream>>>(Bu, lamb, S);
    k_scan_apply<<<NCHUNK, 512, 0, stream>>>(Bu, XsB, lamb, lamN, S);
    // GEMM2: y[L][H] = xs_bf16[L][2P] * Ccat[H][2P]^T + D*u
    k_gemm<false, true><<<(L_DIM / 128) * (H_DIM / 128), 256, 0, stream>>>(
        (const short*)XsB, Ccat, (void*)y, L_DIM, H_DIM, 2 * P_DIM, H_DIM / 128,
        Dv, u_bf);
}

// Round 6
// 78.908 us; speedup vs baseline: 4.9033x; 1.0343x over previous
//
#include <hip/hip_runtime.h>
#include <hip/hip_bf16.h>

#define L_DIM 8192
#define H_DIM 512
#define P_DIM 512
#define CHUNK 32
#define NCHUNK (L_DIM / CHUNK)   // 256

typedef __attribute__((ext_vector_type(8))) short bf16x8;
typedef __attribute__((ext_vector_type(4))) float f32x4;

__device__ inline short f2bf(float x) {
    union { float f; unsigned u; } v; v.f = x;
    unsigned r = v.u + 0x7fffu + ((v.u >> 16) & 1u);
    return (short)(r >> 16);
}
__device__ inline float bflo2f(unsigned w) {
    union { unsigned u; float f; } v; v.u = w << 16; return v.f;
}
__device__ inline float bfhi2f(unsigned w) {
    union { unsigned u; float f; } v; v.u = w & 0xffff0000u; return v.f;
}

__device__ inline void gload_lds16(const void* g, void* l) {
    __builtin_amdgcn_global_load_lds(
        (const __attribute__((address_space(1))) unsigned int*)g,
        (__attribute__((address_space(3))) unsigned int*)l, 16, 0, 0);
}

template<int N> __device__ inline void waitcnt_vm() {
    if constexpr (N == 0)      asm volatile("s_waitcnt vmcnt(0)" ::: "memory");
    else if constexpr (N == 3) asm volatile("s_waitcnt vmcnt(3)" ::: "memory");
    else if constexpr (N == 4) asm volatile("s_waitcnt vmcnt(4)" ::: "memory");
    else if constexpr (N == 6) asm volatile("s_waitcnt vmcnt(6)" ::: "memory");
    else if constexpr (N == 8) asm volatile("s_waitcnt vmcnt(8)" ::: "memory");
}

// ---------------------------------------------------------------------------
// Fused prep:
//   blocks [0,512):        discretize -> Bcat bf16, lambda_bar, lambda_powN
//   blocks [512,1536):     Ccat bf16
//   blocks [1536,3584):    u fp32 -> u_bf bf16
// ---------------------------------------------------------------------------
__global__ __launch_bounds__(256) void k_prep(
        const float* __restrict__ Lre, const float* __restrict__ Lim,
        const float* __restrict__ Bin, const float* __restrict__ log_step,
        const float* __restrict__ Cin, const float* __restrict__ u,
        short* __restrict__ Bcat, short* __restrict__ Ccat,
        short* __restrict__ u_bf,
        float* __restrict__ lambda_bar, float* __restrict__ lambda_powN) {
    const int blk = blockIdx.x;
    const int tid = threadIdx.x;
    if (blk < P_DIM) {
        int p = blk;
        float lr = Lre[p], li = Lim[p];
        float dt = expf(log_step[p]);
        float ar = lr * dt, ai = li * dt;
        float er = expf(ar);
        float lbr = er * cosf(ai);
        float lbi = er * sinf(ai);
        float nr = lbr - 1.0f, ni = lbi;
        float den = lr * lr + li * li;
        float fr = (nr * lr + ni * li) / den;
        float fi = (ni * lr - nr * li) / den;
        if (tid == 0) {
            lambda_bar[2 * p] = lbr;
            lambda_bar[2 * p + 1] = lbi;
            float eN = expf(ar * (float)CHUNK);
            lambda_powN[2 * p] = eN * cosf(ai * (float)CHUNK);
            lambda_powN[2 * p + 1] = eN * sinf(ai * (float)CHUNK);
        }
        for (int h = tid; h < H_DIM; h += 256) {
            float br = Bin[((size_t)p * H_DIM + h) * 2 + 0];
            float bi = Bin[((size_t)p * H_DIM + h) * 2 + 1];
            Bcat[(size_t)(2 * p) * H_DIM + h] = f2bf(fr * br - fi * bi);
            Bcat[(size_t)(2 * p + 1) * H_DIM + h] = f2bf(fr * bi + fi * br);
        }
    } else if (blk < P_DIM + 1024) {
        int idx = (blk - P_DIM) * 256 + tid;           // over H*P
        int h = idx >> 9, p = idx & 511;
        float cr = Cin[(size_t)idx * 2 + 0];
        float ci = Cin[(size_t)idx * 2 + 1];
        Ccat[(size_t)h * (2 * P_DIM) + 2 * p + 0] = f2bf(cr);
        Ccat[(size_t)h * (2 * P_DIM) + 2 * p + 1] = f2bf(-ci);
    } else {
        int i = (blk - P_DIM - 1024) * 256 + tid;      // over (L*H)/8
        const float4* uf = (const float4*)u;
        float4 a0 = uf[(size_t)i * 2];
        float4 a1 = uf[(size_t)i * 2 + 1];
        bf16x8 sv;
        sv[0] = f2bf(a0.x); sv[1] = f2bf(a0.y); sv[2] = f2bf(a0.z); sv[3] = f2bf(a0.w);
        sv[4] = f2bf(a1.x); sv[5] = f2bf(a1.y); sv[6] = f2bf(a1.z); sv[7] = f2bf(a1.w);
        *(bf16x8*)&u_bf[(size_t)i * 8] = sv;
    }
}

// ---------------------------------------------------------------------------
// MFMA GEMM, counted-vmcnt 3-buffer pipeline, swizzled LDS.
//   out[M][N] = A[M][K] * B[N][K]^T, A/B bf16.
//   BM=128, BK=32, BN template (128 or 64). 4 waves (2x2). frags 4 x (BN/32).
//   LDS tile row = 64B = 4 x 16B slots; swizzle slot ^= (row ^ row>>2)&3,
//   applied on the global source of global_load_lds AND on the ds_read addr.
//   Pipeline: 2-deep prefetch, s_waitcnt vmcnt(2*LPS) + raw s_barrier
//   (loads never drain in the main loop); tail peels vmcnt(LPS)/vmcnt(0).
//   OBF16=1: store bf16 (GEMM1 -> Bu packed). EPI: out += Dv[n]*bf2f(Ubf).
// 1-D grid, bijective XCD swizzle (nwg % 8 == 0).
// ---------------------------------------------------------------------------
template<int BN, bool OBF16, bool EPI>
__global__ __launch_bounds__(256) void k_gemm(
        const short* __restrict__ A, const short* __restrict__ B,
        void* __restrict__ Cout, int M, int N, int K, int nwgn,
        const float* __restrict__ Dv, const short* __restrict__ Ubf) {
    constexpr int NF = BN / 32;            // B frags per wave
    constexpr int LPS = 2 + BN / 64;       // gload_lds insts per thread per stage
    __shared__ short As[3][128 * 32];
    __shared__ short Bs[3][BN * 32];

    const int tid = threadIdx.x;
    const int lane = tid & 63;
    const int wid = tid >> 6;
    const int wr = wid >> 1, wc = wid & 1;

    const int nwg = gridDim.x;
    const int orig = blockIdx.x;
    const int id = (orig & 7) * (nwg >> 3) + (orig >> 3);
    const int bm = (id / nwgn) * 128;
    const int bn = (id % nwgn) * BN;

    f32x4 acc[4][NF] = {};
    const int arow = wr * 64 + (lane & 15);
    const int brow = wc * (BN / 2) + (lane & 15);
    // swizzled read slot (lane-constant): slot = (lane>>4) ^ (row^row>>2)&3,
    // with (row)&3 == lane&3 and (row>>2)&3 == (lane>>2)&3 for all frag rows.
    const int rslot = (((lane >> 4) ^ (lane & 3) ^ ((lane >> 2) & 3)) << 4);

    auto stage = [&](int buf, int kk) {
#pragma unroll
        for (int q = 0; q < 2; ++q) {              // A: 8192B / (256thr*16B)
            int sb = q * 4096 + tid * 16;
            int row = sb >> 6, slot = (sb >> 4) & 3;
            int gs = slot ^ ((row ^ (row >> 2)) & 3);
            const char* src = (const char*)A + ((size_t)(bm + row) * K + kk) * 2 + gs * 16;
            gload_lds16(src, (char*)&As[buf][0] + sb);
        }
#pragma unroll
        for (int q = 0; q < BN / 64; ++q) {        // B: BN*64B
            int sb = q * 4096 + tid * 16;
            int row = sb >> 6, slot = (sb >> 4) & 3;
            int gs = slot ^ ((row ^ (row >> 2)) & 3);
            const char* src = (const char*)B + ((size_t)(bn + row) * K + kk) * 2 + gs * 16;
            gload_lds16(src, (char*)&Bs[buf][0] + sb);
        }
    };

    const int nt = K >> 5;
    stage(0, 0);
    stage(1, 32);

    int cur = 0, stg = 2;
    for (int t = 0; t < nt; ++t) {
        if (t + 2 < nt) {
            stage(stg, (t + 2) * 32);
            waitcnt_vm<2 * LPS>();
        } else if (t + 1 < nt) {
            waitcnt_vm<LPS>();
        } else {
            waitcnt_vm<0>();
        }
        __builtin_amdgcn_s_barrier();
        __builtin_amdgcn_sched_barrier(0);

        const char* Ab = (const char*)&As[cur][0];
        const char* Bb = (const char*)&Bs[cur][0];
        bf16x8 af[4], bfr[NF];
#pragma unroll
        for (int m = 0; m < 4; ++m)
            af[m] = *(const bf16x8*)(Ab + (arow + m * 16) * 64 + rslot);
#pragma unroll
        for (int n = 0; n < NF; ++n)
            bfr[n] = *(const bf16x8*)(Bb + (brow + n * 16) * 64 + rslot);
#pragma unroll
        for (int m = 0; m < 4; ++m)
#pragma unroll
            for (int n = 0; n < NF; ++n)
                acc[m][n] = __builtin_amdgcn_mfma_f32_16x16x32_bf16(af[m], bfr[n], acc[m][n], 0, 0, 0);

        if (t + 1 < nt) __builtin_amdgcn_s_barrier();
        cur = (cur == 2) ? 0 : cur + 1;
        stg = (stg == 2) ? 0 : stg + 1;
    }

    const int fq = lane >> 4, fr = lane & 15;
#pragma unroll
    for (int m = 0; m < 4; ++m) {
#pragma unroll
        for (int n = 0; n < NF; ++n) {
            int col = bn + wc * (BN / 2) + n * 16 + fr;
            int row0 = bm + wr * 64 + m * 16 + fq * 4;
#pragma unroll
            for (int j = 0; j < 4; ++j) {
                int row = row0 + j;
                float v = acc[m][n][j];
                if (OBF16) {
                    ((short*)Cout)[(size_t)row * N + col] = f2bf(v);
                } else {
                    if (EPI) {
                        union { unsigned u; float f; } ub;
                        ub.u = ((unsigned)(unsigned short)Ubf[(size_t)row * N + col]) << 16;
                        v += Dv[col] * ub.f;
                    }
                    ((float*)Cout)[(size_t)row * N + col] = v;
                }
            }
        }
    }
}

// ---------------------------------------------------------------------------
// Scan. Bu stored as packed bf16 (re = lo16 @ col 2p, im = hi16 @ col 2p+1).
// ---------------------------------------------------------------------------
__global__ __launch_bounds__(256) void k_scan_summary(const unsigned* __restrict__ Bu,
                                                      const float* __restrict__ lambda_bar,
                                                      float* __restrict__ S) {
    int gid = blockIdx.x * blockDim.x + threadIdx.x;   // NCHUNK*P threads
    int c = gid >> 9, p = gid & 511;
    float lr = lambda_bar[2 * p], li = lambda_bar[2 * p + 1];
    float xr = 0.f, xi = 0.f;
    const unsigned* bu = Bu + (size_t)c * CHUNK * P_DIM + p;
#pragma unroll 4
    for (int j = 0; j < CHUNK; ++j) {
        unsigned w = bu[(size_t)j * P_DIM];
        float br = bflo2f(w), bi = bfhi2f(w);
        float nxr = lr * xr - li * xi + br;
        float nxi = lr * xi + li * xr + bi;
        xr = nxr; xi = nxi;
    }
    ((float2*)S)[(size_t)c * P_DIM + p] = make_float2(xr, xi);
}

// One block per chunk (512 threads = channels). Reconstructs its prefix from
// S via lambda^N-weighted accumulation, scans its chunk, writes packed bf16.
__global__ __launch_bounds__(512) void k_scan_apply(const unsigned* __restrict__ Bu,
                                                    unsigned* __restrict__ XsB,
                                                    const float* __restrict__ lambda_bar,
                                                    const float* __restrict__ lambda_powN,
                                                    const float* __restrict__ S) {
    const int c = blockIdx.x;
    const int p = threadIdx.x;
    const float lNr = lambda_powN[2 * p], lNi = lambda_powN[2 * p + 1];
    float xr = 0.f, xi = 0.f;
    const float2* Sp = (const float2*)S;
    int d = 0;
    while (d + 8 <= c) {
        float2 sb[8];
#pragma unroll
        for (int j = 0; j < 8; ++j) sb[j] = Sp[(size_t)(d + j) * P_DIM + p];
#pragma unroll
        for (int j = 0; j < 8; ++j) {
            float nxr = lNr * xr - lNi * xi + sb[j].x;
            float nxi = lNr * xi + lNi * xr + sb[j].y;
            xr = nxr; xi = nxi;
        }
        d += 8;
    }
    for (; d < c; ++d) {
        float2 s = Sp[(size_t)d * P_DIM + p];
        float nxr = lNr * xr - lNi * xi + s.x;
        float nxi = lNr * xi + lNi * xr + s.y;
        xr = nxr; xi = nxi;
    }
    const float lr = lambda_bar[2 * p], li = lambda_bar[2 * p + 1];
    const unsigned* bu = Bu + (size_t)c * CHUNK * P_DIM + p;
#pragma unroll 4
    for (int j = 0; j < CHUNK; ++j) {
        unsigned w = bu[(size_t)j * P_DIM];
        float br = bflo2f(w), bi = bfhi2f(w);
        float nxr = lr * xr - li * xi + br;
        float nxi = lr * xi + li * xr + bi;
        xr = nxr; xi = nxi;
        unsigned pk = (unsigned)(unsigned short)f2bf(xr)
                    | ((unsigned)(unsigned short)f2bf(xi) << 16);
        XsB[((size_t)c * CHUNK + j) * P_DIM + p] = pk;
    }
}

// ---------------------------------------------------------------------------
extern "C" void kernel_launch(void* const* d_in, const int* in_sizes, int n_in,
                              void* d_out, int out_size, void* d_ws, size_t ws_size,
                              hipStream_t stream) {
    const float* u        = (const float*)d_in[0];
    const float* Lre      = (const float*)d_in[1];
    const float* Lim      = (const float*)d_in[2];
    const float* Bin      = (const float*)d_in[3];
    const float* Cin      = (const float*)d_in[4];
    const float* Dv       = (const float*)d_in[5];
    const float* log_step = (const float*)d_in[6];
    float* y = (float*)d_out;

    char* w = (char*)d_ws;
    size_t off = 0;
    short* Bcat = (short*)(w + off); off += (size_t)2 * P_DIM * H_DIM * 2;   // 1 MB
    short* Ccat = (short*)(w + off); off += (size_t)2 * P_DIM * H_DIM * 2;   // 1 MB
    float* lamb = (float*)(w + off); off += 2 * P_DIM * 4;
    float* lamN = (float*)(w + off); off += 2 * P_DIM * 4;
    float* S    = (float*)(w + off); off += (size_t)NCHUNK * 2 * P_DIM * 4;  // 1 MB
    unsigned* Bu  = (unsigned*)(w + off); off += (size_t)L_DIM * P_DIM * 4;  // 16 MB (packed bf16)
    unsigned* XsB = (unsigned*)(w + off); off += (size_t)L_DIM * P_DIM * 4;  // 16 MB (packed bf16)
    short* u_bf   = (short*)(w + off);   off += (size_t)L_DIM * H_DIM * 2;   // 8 MB

    // prep: discretize + Ccat + u->bf16
    k_prep<<<P_DIM + 1024 + 2048, 256, 0, stream>>>(
        Lre, Lim, Bin, log_step, Cin, u, Bcat, Ccat, u_bf, lamb, lamN);
    // GEMM1: Bu[L][2P](bf16 packed) = u_bf[L][H] * Bcat[2P][H]^T
    k_gemm<128, true, false><<<(L_DIM / 128) * ((2 * P_DIM) / 128), 256, 0, stream>>>(
        u_bf, Bcat, (void*)Bu, L_DIM, 2 * P_DIM, H_DIM, (2 * P_DIM) / 128,
        nullptr, nullptr);
    // Scan
    k_scan_summary<<<(NCHUNK * P_DIM) / 256, 256, 0, stream>>>(Bu, lamb, S);
    k_scan_apply<<<NCHUNK, 512, 0, stream>>>(Bu, XsB, lamb, lamN, S);
    // GEMM2: y[L][H] = xs_bf16[L][2P] * Ccat[H][2P]^T + D*u   (BN=64 -> 512 wgs)
    k_gemm<64, false, true><<<(L_DIM / 128) * (H_DIM / 64), 256, 0, stream>>>(
        (const short*)XsB, Ccat, (void*)y, L_DIM, H_DIM, 2 * P_DIM, H_DIM / 64,
        Dv, u_bf);
}

// Round 7
// 69.685 us; speedup vs baseline: 5.5522x; 1.1323x over previous
//
#include <hip/hip_runtime.h>
#include <hip/hip_bf16.h>

#define L_DIM 8192
#define H_DIM 512
#define P_DIM 512
#define CHUNK 32
#define NCHUNK (L_DIM / CHUNK)   // 256

typedef __attribute__((ext_vector_type(8))) short bf16x8;
typedef __attribute__((ext_vector_type(4))) float f32x4;

__device__ inline short f2bf(float x) {
    union { float f; unsigned u; } v; v.f = x;
    unsigned r = v.u + 0x7fffu + ((v.u >> 16) & 1u);
    return (short)(r >> 16);
}
__device__ inline float bflo2f(unsigned w) {
    union { unsigned u; float f; } v; v.u = w << 16; return v.f;
}
__device__ inline float bfhi2f(unsigned w) {
    union { unsigned u; float f; } v; v.u = w & 0xffff0000u; return v.f;
}

__device__ inline void gload_lds16(const void* g, void* l) {
    __builtin_amdgcn_global_load_lds(
        (const __attribute__((address_space(1))) unsigned int*)g,
        (__attribute__((address_space(3))) unsigned int*)l, 16, 0, 0);
}

template<int N> __device__ inline void waitcnt_vm() {
    if constexpr (N == 0)      asm volatile("s_waitcnt vmcnt(0)" ::: "memory");
    else if constexpr (N == 3) asm volatile("s_waitcnt vmcnt(3)" ::: "memory");
    else if constexpr (N == 4) asm volatile("s_waitcnt vmcnt(4)" ::: "memory");
    else if constexpr (N == 6) asm volatile("s_waitcnt vmcnt(6)" ::: "memory");
    else if constexpr (N == 8) asm volatile("s_waitcnt vmcnt(8)" ::: "memory");
}

// ---------------------------------------------------------------------------
// Fused prep:
//   blocks [0,512):        discretize -> Bcat bf16, lambda_bar, lambda_powN
//   blocks [512,1536):     Ccat bf16
//   blocks [1536,3584):    u fp32 -> u_bf bf16
// ---------------------------------------------------------------------------
__global__ __launch_bounds__(256) void k_prep(
        const float* __restrict__ Lre, const float* __restrict__ Lim,
        const float* __restrict__ Bin, const float* __restrict__ log_step,
        const float* __restrict__ Cin, const float* __restrict__ u,
        short* __restrict__ Bcat, short* __restrict__ Ccat,
        short* __restrict__ u_bf,
        float* __restrict__ lambda_bar, float* __restrict__ lambda_powN) {
    const int blk = blockIdx.x;
    const int tid = threadIdx.x;
    if (blk < P_DIM) {
        int p = blk;
        float lr = Lre[p], li = Lim[p];
        float dt = expf(log_step[p]);
        float ar = lr * dt, ai = li * dt;
        float er = expf(ar);
        float lbr = er * cosf(ai);
        float lbi = er * sinf(ai);
        float nr = lbr - 1.0f, ni = lbi;
        float den = lr * lr + li * li;
        float fr = (nr * lr + ni * li) / den;
        float fi = (ni * lr - nr * li) / den;
        if (tid == 0) {
            lambda_bar[2 * p] = lbr;
            lambda_bar[2 * p + 1] = lbi;
            float eN = expf(ar * (float)CHUNK);
            lambda_powN[2 * p] = eN * cosf(ai * (float)CHUNK);
            lambda_powN[2 * p + 1] = eN * sinf(ai * (float)CHUNK);
        }
        for (int h = tid; h < H_DIM; h += 256) {
            float br = Bin[((size_t)p * H_DIM + h) * 2 + 0];
            float bi = Bin[((size_t)p * H_DIM + h) * 2 + 1];
            Bcat[(size_t)(2 * p) * H_DIM + h] = f2bf(fr * br - fi * bi);
            Bcat[(size_t)(2 * p + 1) * H_DIM + h] = f2bf(fr * bi + fi * br);
        }
    } else if (blk < P_DIM + 1024) {
        int idx = (blk - P_DIM) * 256 + tid;           // over H*P
        int h = idx >> 9, p = idx & 511;
        float cr = Cin[(size_t)idx * 2 + 0];
        float ci = Cin[(size_t)idx * 2 + 1];
        Ccat[(size_t)h * (2 * P_DIM) + 2 * p + 0] = f2bf(cr);
        Ccat[(size_t)h * (2 * P_DIM) + 2 * p + 1] = f2bf(-ci);
    } else {
        int i = (blk - P_DIM - 1024) * 256 + tid;      // over (L*H)/8
        const float4* uf = (const float4*)u;
        float4 a0 = uf[(size_t)i * 2];
        float4 a1 = uf[(size_t)i * 2 + 1];
        bf16x8 sv;
        sv[0] = f2bf(a0.x); sv[1] = f2bf(a0.y); sv[2] = f2bf(a0.z); sv[3] = f2bf(a0.w);
        sv[4] = f2bf(a1.x); sv[5] = f2bf(a1.y); sv[6] = f2bf(a1.z); sv[7] = f2bf(a1.w);
        *(bf16x8*)&u_bf[(size_t)i * 8] = sv;
    }
}

// ---------------------------------------------------------------------------
// MFMA GEMM, counted-vmcnt 3-buffer pipeline, swizzled LDS.
//   out[M][N] = A[M][K] * B[N][K]^T, A/B bf16.
//   BM=128, BK=32, BN template (128 or 64). 4 waves (2x2), 16x16x32 MFMA.
//   Swizzle: slot ^= (row ^ row>>2)&3, applied on global src AND ds_read addr.
//   Pipeline: 2-deep prefetch, s_waitcnt vmcnt(2*LPS) + raw s_barrier.
//   OBF16=1: store bf16 (GEMM1 -> Bu packed).  EPI: out += Dv[n]*bf2f(Ubf).
//   SUMM=1 (requires OBF16): after K-loop, dump the block's bf16 Bu tile to
//     LDS short[128][132] and compute per-chunk scan summaries S directly
//     (bit-identical to re-reading Bu from HBM).
// 1-D grid, bijective XCD swizzle (nwg % 8 == 0).
// ---------------------------------------------------------------------------
template<int BN, bool OBF16, bool EPI, bool SUMM>
__global__ __launch_bounds__(256) void k_gemm(
        const short* __restrict__ A, const short* __restrict__ B,
        void* __restrict__ Cout, int M, int N, int K, int nwgn,
        const float* __restrict__ Dv, const short* __restrict__ Ubf,
        const float* __restrict__ Lamb, float* __restrict__ S) {
    constexpr int NF = BN / 32;            // B frags per wave
    constexpr int LPS = 2 + BN / 64;       // gload_lds insts per thread per stage
    constexpr int ASZ = 128 * 32 * 2;      // bytes per A buffer
    constexpr int BSZ = BN * 32 * 2;       // bytes per B buffer
    __shared__ char smem[3 * ASZ + 3 * BSZ];

    const int tid = threadIdx.x;
    const int lane = tid & 63;
    const int wid = tid >> 6;
    const int wr = wid >> 1, wc = wid & 1;

    const int nwg = gridDim.x;
    const int orig = blockIdx.x;
    const int id = (orig & 7) * (nwg >> 3) + (orig >> 3);
    const int bm = (id / nwgn) * 128;
    const int bn = (id % nwgn) * BN;

    f32x4 acc[4][NF] = {};
    const int arow = wr * 64 + (lane & 15);
    const int brow = wc * (BN / 2) + (lane & 15);
    // swizzled read slot (lane-constant)
    const int rslot = (((lane >> 4) ^ (lane & 3) ^ ((lane >> 2) & 3)) << 4);

    auto stage = [&](int buf, int kk) {
#pragma unroll
        for (int q = 0; q < 2; ++q) {              // A: 8192B / (256thr*16B)
            int sb = q * 4096 + tid * 16;
            int row = sb >> 6, slot = (sb >> 4) & 3;
            int gs = slot ^ ((row ^ (row >> 2)) & 3);
            const char* src = (const char*)A + ((size_t)(bm + row) * K + kk) * 2 + gs * 16;
            gload_lds16(src, smem + buf * ASZ + sb);
        }
#pragma unroll
        for (int q = 0; q < BN / 64; ++q) {        // B: BN*64B
            int sb = q * 4096 + tid * 16;
            int row = sb >> 6, slot = (sb >> 4) & 3;
            int gs = slot ^ ((row ^ (row >> 2)) & 3);
            const char* src = (const char*)B + ((size_t)(bn + row) * K + kk) * 2 + gs * 16;
            gload_lds16(src, smem + 3 * ASZ + buf * BSZ + sb);
        }
    };

    const int nt = K >> 5;
    stage(0, 0);
    stage(1, 32);

    int cur = 0, stg = 2;
    for (int t = 0; t < nt; ++t) {
        if (t + 2 < nt) {
            stage(stg, (t + 2) * 32);
            waitcnt_vm<2 * LPS>();
        } else if (t + 1 < nt) {
            waitcnt_vm<LPS>();
        } else {
            waitcnt_vm<0>();
        }
        __builtin_amdgcn_s_barrier();
        __builtin_amdgcn_sched_barrier(0);

        const char* Ab = smem + cur * ASZ;
        const char* Bb = smem + 3 * ASZ + cur * BSZ;
        bf16x8 af[4], bfr[NF];
#pragma unroll
        for (int m = 0; m < 4; ++m)
            af[m] = *(const bf16x8*)(Ab + (arow + m * 16) * 64 + rslot);
#pragma unroll
        for (int n = 0; n < NF; ++n)
            bfr[n] = *(const bf16x8*)(Bb + (brow + n * 16) * 64 + rslot);
        __builtin_amdgcn_s_setprio(1);
#pragma unroll
        for (int m = 0; m < 4; ++m)
#pragma unroll
            for (int n = 0; n < NF; ++n)
                acc[m][n] = __builtin_amdgcn_mfma_f32_16x16x32_bf16(af[m], bfr[n], acc[m][n], 0, 0, 0);
        __builtin_amdgcn_s_setprio(0);

        if (t + 1 < nt) __builtin_amdgcn_s_barrier();
        cur = (cur == 2) ? 0 : cur + 1;
        stg = (stg == 2) ? 0 : stg + 1;
    }

    if (SUMM) __syncthreads();      // all waves done with staging buffers

    const int fq = lane >> 4, fr = lane & 15;
#pragma unroll
    for (int m = 0; m < 4; ++m) {
#pragma unroll
        for (int n = 0; n < NF; ++n) {
            int col = bn + wc * (BN / 2) + n * 16 + fr;
            int row0 = bm + wr * 64 + m * 16 + fq * 4;
#pragma unroll
            for (int j = 0; j < 4; ++j) {
                int row = row0 + j;
                float v = acc[m][n][j];
                if (OBF16) {
                    short s = f2bf(v);
                    ((short*)Cout)[(size_t)row * N + col] = s;
                    if (SUMM) {
                        int rowL = (wr * 64 + m * 16 + fq * 4 + j);
                        int colL = (wc * (BN / 2) + n * 16 + fr);
                        *(short*)(smem + rowL * 264 + colL * 2) = s;   // [128][132]
                    }
                } else {
                    if (EPI) {
                        union { unsigned u; float f; } ub;
                        ub.u = ((unsigned)(unsigned short)Ubf[(size_t)row * N + col]) << 16;
                        v += Dv[col] * ub.f;
                    }
                    ((float*)Cout)[(size_t)row * N + col] = v;
                }
            }
        }
    }

    if (SUMM) {
        __syncthreads();
        // 256 threads -> 4 chunks x 64 channels
        const int c_loc = tid >> 6;          // 0..3
        const int ch = tid & 63;             // 0..63
        const int gch = (bn >> 1) + ch;      // global channel
        const float lr = Lamb[2 * gch], li = Lamb[2 * gch + 1];
        float xr = 0.f, xi = 0.f;
#pragma unroll 8
        for (int j = 0; j < 32; ++j) {
            int rowL = c_loc * 32 + j;
            unsigned wv = *(const unsigned*)(smem + rowL * 264 + ch * 4);
            float br = bflo2f(wv), bi = bfhi2f(wv);
            float nxr = lr * xr - li * xi + br;
            float nxi = lr * xi + li * xr + bi;
            xr = nxr; xi = nxi;
        }
        ((float2*)S)[(size_t)((bm >> 5) + c_loc) * P_DIM + gch] = make_float2(xr, xi);
    }
}

// ---------------------------------------------------------------------------
// Combine: prefix over chunk summaries. 8 blocks x 64 threads (1 ch each),
// sequential in c (same FP order as before), 16-deep batched loads.
// ---------------------------------------------------------------------------
__global__ __launch_bounds__(64) void k_scan_combine(const float* __restrict__ S,
                                                     const float* __restrict__ lambda_powN,
                                                     float* __restrict__ pref) {
    const int ch = blockIdx.x * 64 + threadIdx.x;
    const float lNr = lambda_powN[2 * ch], lNi = lambda_powN[2 * ch + 1];
    float xr = 0.f, xi = 0.f;
    const float2* Sp = (const float2*)S;
    float2* Pp = (float2*)pref;
    for (int c0 = 0; c0 < NCHUNK; c0 += 16) {
        float2 sb[16];
#pragma unroll
        for (int j = 0; j < 16; ++j) sb[j] = Sp[(size_t)(c0 + j) * P_DIM + ch];
#pragma unroll
        for (int j = 0; j < 16; ++j) {
            Pp[(size_t)(c0 + j) * P_DIM + ch] = make_float2(xr, xi);
            float nxr = lNr * xr - lNi * xi + sb[j].x;
            float nxi = lNr * xi + lNi * xr + sb[j].y;
            xr = nxr; xi = nxi;
        }
    }
}

// ---------------------------------------------------------------------------
// Apply: fully parallel, prefix given. Bu packed bf16 -> XsB packed bf16.
// ---------------------------------------------------------------------------
__global__ __launch_bounds__(256) void k_scan_apply(const unsigned* __restrict__ Bu,
                                                    unsigned* __restrict__ XsB,
                                                    const float* __restrict__ lambda_bar,
                                                    const float* __restrict__ pref) {
    int gid = blockIdx.x * blockDim.x + threadIdx.x;   // NCHUNK*P threads
    int c = gid >> 9, p = gid & 511;
    const float lr = lambda_bar[2 * p], li = lambda_bar[2 * p + 1];
    float2 x0 = ((const float2*)pref)[(size_t)c * P_DIM + p];
    float xr = x0.x, xi = x0.y;
    const unsigned* bu = Bu + (size_t)c * CHUNK * P_DIM + p;
#pragma unroll 4
    for (int j = 0; j < CHUNK; ++j) {
        unsigned w = bu[(size_t)j * P_DIM];
        float br = bflo2f(w), bi = bfhi2f(w);
        float nxr = lr * xr - li * xi + br;
        float nxi = lr * xi + li * xr + bi;
        xr = nxr; xi = nxi;
        unsigned pk = (unsigned)(unsigned short)f2bf(xr)
                    | ((unsigned)(unsigned short)f2bf(xi) << 16);
        XsB[((size_t)c * CHUNK + j) * P_DIM + p] = pk;
    }
}

// ---------------------------------------------------------------------------
extern "C" void kernel_launch(void* const* d_in, const int* in_sizes, int n_in,
                              void* d_out, int out_size, void* d_ws, size_t ws_size,
                              hipStream_t stream) {
    const float* u        = (const float*)d_in[0];
    const float* Lre      = (const float*)d_in[1];
    const float* Lim      = (const float*)d_in[2];
    const float* Bin      = (const float*)d_in[3];
    const float* Cin      = (const float*)d_in[4];
    const float* Dv       = (const float*)d_in[5];
    const float* log_step = (const float*)d_in[6];
    float* y = (float*)d_out;

    char* w = (char*)d_ws;
    size_t off = 0;
    short* Bcat = (short*)(w + off); off += (size_t)2 * P_DIM * H_DIM * 2;   // 1 MB
    short* Ccat = (short*)(w + off); off += (size_t)2 * P_DIM * H_DIM * 2;   // 1 MB
    float* lamb = (float*)(w + off); off += 2 * P_DIM * 4;
    float* lamN = (float*)(w + off); off += 2 * P_DIM * 4;
    float* S    = (float*)(w + off); off += (size_t)NCHUNK * 2 * P_DIM * 4;  // 1 MB
    float* pref = (float*)(w + off); off += (size_t)NCHUNK * 2 * P_DIM * 4;  // 1 MB
    unsigned* Bu  = (unsigned*)(w + off); off += (size_t)L_DIM * P_DIM * 4;  // 16 MB (packed bf16)
    unsigned* XsB = (unsigned*)(w + off); off += (size_t)L_DIM * P_DIM * 4;  // 16 MB (packed bf16)
    short* u_bf   = (short*)(w + off);   off += (size_t)L_DIM * H_DIM * 2;   // 8 MB

    // prep: discretize + Ccat + u->bf16
    k_prep<<<P_DIM + 1024 + 2048, 256, 0, stream>>>(
        Lre, Lim, Bin, log_step, Cin, u, Bcat, Ccat, u_bf, lamb, lamN);
    // GEMM1 (+fused chunk summaries): Bu[L][2P](bf16 packed) = u_bf * Bcat^T
    k_gemm<128, true, false, true><<<(L_DIM / 128) * ((2 * P_DIM) / 128), 256, 0, stream>>>(
        u_bf, Bcat, (void*)Bu, L_DIM, 2 * P_DIM, H_DIM, (2 * P_DIM) / 128,
        nullptr, nullptr, lamb, S);
    // Combine + apply
    k_scan_combine<<<8, 64, 0, stream>>>(S, lamN, pref);
    k_scan_apply<<<(NCHUNK * P_DIM) / 256, 256, 0, stream>>>(Bu, XsB, lamb, pref);
    // GEMM2: y[L][H] = xs_bf16[L][2P] * Ccat[H][2P]^T + D*u   (BN=64 -> 512 wgs)
    k_gemm<64, false, true, false><<<(L_DIM / 128) * (H_DIM / 64), 256, 0, stream>>>(
        (const short*)XsB, Ccat, (void*)y, L_DIM, H_DIM, 2 * P_DIM, H_DIM / 64,
        Dv, u_bf, nullptr, nullptr);
}

// Round 8
// 67.632 us; speedup vs baseline: 5.7208x; 1.0304x over previous
//
#include <hip/hip_runtime.h>
#include <hip/hip_bf16.h>

#define L_DIM 8192
#define H_DIM 512
#define P_DIM 512
#define CHUNK 32
#define NCHUNK (L_DIM / CHUNK)   // 256

typedef __attribute__((ext_vector_type(8))) short bf16x8;
typedef __attribute__((ext_vector_type(4))) float f32x4;

__device__ inline short f2bf(float x) {
    union { float f; unsigned u; } v; v.f = x;
    unsigned r = v.u + 0x7fffu + ((v.u >> 16) & 1u);
    return (short)(r >> 16);
}
__device__ inline float bflo2f(unsigned w) {
    union { unsigned u; float f; } v; v.u = w << 16; return v.f;
}
__device__ inline float bfhi2f(unsigned w) {
    union { unsigned u; float f; } v; v.u = w & 0xffff0000u; return v.f;
}

__device__ inline void gload_lds16(const void* g, void* l) {
    __builtin_amdgcn_global_load_lds(
        (const __attribute__((address_space(1))) unsigned int*)g,
        (__attribute__((address_space(3))) unsigned int*)l, 16, 0, 0);
}

template<int N> __device__ inline void waitcnt_vm() {
    if constexpr (N == 0)      asm volatile("s_waitcnt vmcnt(0)" ::: "memory");
    else if constexpr (N == 3) asm volatile("s_waitcnt vmcnt(3)" ::: "memory");
    else if constexpr (N == 4) asm volatile("s_waitcnt vmcnt(4)" ::: "memory");
    else if constexpr (N == 6) asm volatile("s_waitcnt vmcnt(6)" ::: "memory");
    else if constexpr (N == 8) asm volatile("s_waitcnt vmcnt(8)" ::: "memory");
}

// ---------------------------------------------------------------------------
// Fused prep:
//   blocks [0,512):        discretize -> Bcat bf16, lambda_bar, lambda_powN
//   blocks [512,1536):     Ccat bf16
//   blocks [1536,3584):    u fp32 -> u_bf bf16
// ---------------------------------------------------------------------------
__global__ __launch_bounds__(256) void k_prep(
        const float* __restrict__ Lre, const float* __restrict__ Lim,
        const float* __restrict__ Bin, const float* __restrict__ log_step,
        const float* __restrict__ Cin, const float* __restrict__ u,
        short* __restrict__ Bcat, short* __restrict__ Ccat,
        short* __restrict__ u_bf,
        float* __restrict__ lambda_bar, float* __restrict__ lambda_powN) {
    const int blk = blockIdx.x;
    const int tid = threadIdx.x;
    if (blk < P_DIM) {
        int p = blk;
        float lr = Lre[p], li = Lim[p];
        float dt = expf(log_step[p]);
        float ar = lr * dt, ai = li * dt;
        float er = expf(ar);
        float lbr = er * cosf(ai);
        float lbi = er * sinf(ai);
        float nr = lbr - 1.0f, ni = lbi;
        float den = lr * lr + li * li;
        float fr = (nr * lr + ni * li) / den;
        float fi = (ni * lr - nr * li) / den;
        if (tid == 0) {
            lambda_bar[2 * p] = lbr;
            lambda_bar[2 * p + 1] = lbi;
            float eN = expf(ar * (float)CHUNK);
            lambda_powN[2 * p] = eN * cosf(ai * (float)CHUNK);
            lambda_powN[2 * p + 1] = eN * sinf(ai * (float)CHUNK);
        }
        for (int h = tid; h < H_DIM; h += 256) {
            float br = Bin[((size_t)p * H_DIM + h) * 2 + 0];
            float bi = Bin[((size_t)p * H_DIM + h) * 2 + 1];
            Bcat[(size_t)(2 * p) * H_DIM + h] = f2bf(fr * br - fi * bi);
            Bcat[(size_t)(2 * p + 1) * H_DIM + h] = f2bf(fr * bi + fi * br);
        }
    } else if (blk < P_DIM + 1024) {
        int idx = (blk - P_DIM) * 256 + tid;           // over H*P
        int h = idx >> 9, p = idx & 511;
        float cr = Cin[(size_t)idx * 2 + 0];
        float ci = Cin[(size_t)idx * 2 + 1];
        Ccat[(size_t)h * (2 * P_DIM) + 2 * p + 0] = f2bf(cr);
        Ccat[(size_t)h * (2 * P_DIM) + 2 * p + 1] = f2bf(-ci);
    } else {
        int i = (blk - P_DIM - 1024) * 256 + tid;      // over (L*H)/8
        const float4* uf = (const float4*)u;
        float4 a0 = uf[(size_t)i * 2];
        float4 a1 = uf[(size_t)i * 2 + 1];
        bf16x8 sv;
        sv[0] = f2bf(a0.x); sv[1] = f2bf(a0.y); sv[2] = f2bf(a0.z); sv[3] = f2bf(a0.w);
        sv[4] = f2bf(a1.x); sv[5] = f2bf(a1.y); sv[6] = f2bf(a1.z); sv[7] = f2bf(a1.w);
        *(bf16x8*)&u_bf[(size_t)i * 8] = sv;
    }
}

// ---------------------------------------------------------------------------
// MFMA GEMM, counted-vmcnt 3-buffer pipeline, swizzled LDS, LDS epilogue.
//   out[M][N] = A[M][K] * B[N][K]^T, A/B bf16.
//   BM=128, BK=32, BN template (128 or 64). 4 waves (2x2), 16x16x32 MFMA.
//   Staging swizzle: slot ^= (row ^ row>>2)&3 on global src AND ds_read addr.
//   Pipeline: 2-deep prefetch, s_waitcnt vmcnt(2*LPS) + raw s_barrier.
//   Epilogue: acc -> LDS tile (row stride 272 B) -> fully coalesced 16B
//   global stores. OBF16: bf16 out (+SUMM: fused per-chunk scan summaries).
//   EPI: out += Dv[n]*bf2f(Ubf[m][n]) with coalesced Ubf/Dv loads.
// 1-D grid, bijective XCD swizzle (nwg % 8 == 0).
// ---------------------------------------------------------------------------
template<int BN, bool OBF16, bool EPI, bool SUMM>
__global__ __launch_bounds__(256) void k_gemm(
        const short* __restrict__ A, const short* __restrict__ B,
        void* __restrict__ Cout, int M, int N, int K, int nwgn,
        const float* __restrict__ Dv, const short* __restrict__ Ubf,
        const float* __restrict__ Lamb, float* __restrict__ S) {
    constexpr int NF = BN / 32;            // B frags per wave
    constexpr int LPS = 2 + BN / 64;       // gload_lds insts per thread per stage
    constexpr int ASZ = 128 * 32 * 2;      // bytes per A buffer
    constexpr int BSZ = BN * 32 * 2;       // bytes per B buffer
    constexpr int STG = 3 * (ASZ + BSZ);
    constexpr int TILE = 128 * 272;        // epilogue tile (both dtypes)
    constexpr int SMEM_SZ = STG > TILE ? STG : TILE;
    __shared__ __align__(16) char smem[SMEM_SZ];

    const int tid = threadIdx.x;
    const int lane = tid & 63;
    const int wid = tid >> 6;
    const int wr = wid >> 1, wc = wid & 1;

    const int nwg = gridDim.x;
    const int orig = blockIdx.x;
    const int id = (orig & 7) * (nwg >> 3) + (orig >> 3);
    const int bm = (id / nwgn) * 128;
    const int bn = (id % nwgn) * BN;

    f32x4 acc[4][NF] = {};
    const int arow = wr * 64 + (lane & 15);
    const int brow = wc * (BN / 2) + (lane & 15);
    const int rslot = (((lane >> 4) ^ (lane & 3) ^ ((lane >> 2) & 3)) << 4);

    auto stage = [&](int buf, int kk) {
#pragma unroll
        for (int q = 0; q < 2; ++q) {              // A: 8192B / (256thr*16B)
            int sb = q * 4096 + tid * 16;
            int row = sb >> 6, slot = (sb >> 4) & 3;
            int gs = slot ^ ((row ^ (row >> 2)) & 3);
            const char* src = (const char*)A + ((size_t)(bm + row) * K + kk) * 2 + gs * 16;
            gload_lds16(src, smem + buf * ASZ + sb);
        }
#pragma unroll
        for (int q = 0; q < BN / 64; ++q) {        // B: BN*64B
            int sb = q * 4096 + tid * 16;
            int row = sb >> 6, slot = (sb >> 4) & 3;
            int gs = slot ^ ((row ^ (row >> 2)) & 3);
            const char* src = (const char*)B + ((size_t)(bn + row) * K + kk) * 2 + gs * 16;
            gload_lds16(src, smem + 3 * ASZ + buf * BSZ + sb);
        }
    };

    const int nt = K >> 5;
    stage(0, 0);
    stage(1, 32);

    int cur = 0, stg = 2;
    for (int t = 0; t < nt; ++t) {
        if (t + 2 < nt) {
            stage(stg, (t + 2) * 32);
            waitcnt_vm<2 * LPS>();
        } else if (t + 1 < nt) {
            waitcnt_vm<LPS>();
        } else {
            waitcnt_vm<0>();
        }
        __builtin_amdgcn_s_barrier();
        __builtin_amdgcn_sched_barrier(0);

        const char* Ab = smem + cur * ASZ;
        const char* Bb = smem + 3 * ASZ + cur * BSZ;
        bf16x8 af[4], bfr[NF];
#pragma unroll
        for (int m = 0; m < 4; ++m)
            af[m] = *(const bf16x8*)(Ab + (arow + m * 16) * 64 + rslot);
#pragma unroll
        for (int n = 0; n < NF; ++n)
            bfr[n] = *(const bf16x8*)(Bb + (brow + n * 16) * 64 + rslot);
        __builtin_amdgcn_s_setprio(1);
#pragma unroll
        for (int m = 0; m < 4; ++m)
#pragma unroll
            for (int n = 0; n < NF; ++n)
                acc[m][n] = __builtin_amdgcn_mfma_f32_16x16x32_bf16(af[m], bfr[n], acc[m][n], 0, 0, 0);
        __builtin_amdgcn_s_setprio(0);

        if (t + 1 < nt) __builtin_amdgcn_s_barrier();
        cur = (cur == 2) ? 0 : cur + 1;
        stg = (stg == 2) ? 0 : stg + 1;
    }

    // ------------------- epilogue via LDS tile (272 B rows) -------------------
    __syncthreads();          // all waves done with staging buffers
    const int fq = lane >> 4, fr = lane & 15;

    if (OBF16) {
#pragma unroll
        for (int m = 0; m < 4; ++m)
#pragma unroll
            for (int n = 0; n < NF; ++n) {
                int rowL = wr * 64 + m * 16 + fq * 4;
                int colL = wc * (BN / 2) + n * 16 + fr;
#pragma unroll
                for (int j = 0; j < 4; ++j)
                    *(short*)(smem + (rowL + j) * 272 + colL * 2) = f2bf(acc[m][n][j]);
            }
        __syncthreads();
        constexpr int SEGS = BN / 8;              // 16B segments per row
#pragma unroll
        for (int it = 0; it < (128 * SEGS) / 256; ++it) {
            int f = it * 256 + tid;
            int row = f / SEGS, seg = f % SEGS;
            uint4 v = *(const uint4*)(smem + row * 272 + seg * 16);
            *(uint4*)((short*)Cout + (size_t)(bm + row) * N + bn + seg * 8) = v;
        }
        if (SUMM) {
            // 256 threads -> 4 chunks x 64 complex channels
            const int c_loc = tid >> 6;
            const int ch = tid & 63;
            const int gch = (bn >> 1) + ch;
            const float lr = Lamb[2 * gch], li = Lamb[2 * gch + 1];
            float xr = 0.f, xi = 0.f;
#pragma unroll 8
            for (int j = 0; j < 32; ++j) {
                unsigned wv = *(const unsigned*)(smem + (c_loc * 32 + j) * 272 + ch * 4);
                float br = bflo2f(wv), bi = bfhi2f(wv);
                float nxr = lr * xr - li * xi + br;
                float nxi = lr * xi + li * xr + bi;
                xr = nxr; xi = nxi;
            }
            ((float2*)S)[(size_t)((bm >> 5) + c_loc) * P_DIM + gch] = make_float2(xr, xi);
        }
    } else {
#pragma unroll
        for (int m = 0; m < 4; ++m)
#pragma unroll
            for (int n = 0; n < NF; ++n) {
                int rowL = wr * 64 + m * 16 + fq * 4;
                int colL = wc * (BN / 2) + n * 16 + fr;
#pragma unroll
                for (int j = 0; j < 4; ++j)
                    *(float*)(smem + (rowL + j) * 272 + colL * 4) = acc[m][n][j];
            }
        __syncthreads();
        constexpr int SEGS = BN / 4;              // 16B segments per row (f32)
#pragma unroll
        for (int it = 0; it < (128 * SEGS) / 256; ++it) {
            int f = it * 256 + tid;
            int row = f / SEGS, seg = f % SEGS;
            float4 v = *(const float4*)(smem + row * 272 + seg * 16);
            int gr = bm + row, gc = bn + seg * 4;
            if (EPI) {
                const short* up = Ubf + (size_t)gr * N + gc;
                short4 us = *(const short4*)up;
                float4 dv = *(const float4*)(Dv + gc);
                v.x += dv.x * bflo2f((unsigned)(unsigned short)us.x);
                v.y += dv.y * bflo2f((unsigned)(unsigned short)us.y);
                v.z += dv.z * bflo2f((unsigned)(unsigned short)us.z);
                v.w += dv.w * bflo2f((unsigned)(unsigned short)us.w);
            }
            *(float4*)((float*)Cout + (size_t)gr * N + gc) = v;
        }
    }
}

// ---------------------------------------------------------------------------
// Combine: prefix over chunk summaries. 8 blocks x 64 threads (1 ch each),
// sequential in c (same FP order as before), register double-buffered
// 16-deep batches so L2 latency hides under the 16-step compute.
// ---------------------------------------------------------------------------
__global__ __launch_bounds__(64) void k_scan_combine(const float* __restrict__ S,
                                                     const float* __restrict__ lambda_powN,
                                                     float* __restrict__ pref) {
    const int ch = blockIdx.x * 64 + threadIdx.x;
    const float lNr = lambda_powN[2 * ch], lNi = lambda_powN[2 * ch + 1];
    const float2* Sp = (const float2*)S;
    float2* Pp = (float2*)pref;
    float2 curb[16], nxtb[16];
#pragma unroll
    for (int j = 0; j < 16; ++j) curb[j] = Sp[(size_t)j * P_DIM + ch];
    float xr = 0.f, xi = 0.f;
    for (int c0 = 0; c0 < NCHUNK; c0 += 16) {
        if (c0 + 16 < NCHUNK) {
#pragma unroll
            for (int j = 0; j < 16; ++j) nxtb[j] = Sp[(size_t)(c0 + 16 + j) * P_DIM + ch];
        }
#pragma unroll
        for (int j = 0; j < 16; ++j) {
            Pp[(size_t)(c0 + j) * P_DIM + ch] = make_float2(xr, xi);
            float nxr = lNr * xr - lNi * xi + curb[j].x;
            float nxi = lNr * xi + lNi * xr + curb[j].y;
            xr = nxr; xi = nxi;
        }
#pragma unroll
        for (int j = 0; j < 16; ++j) curb[j] = nxtb[j];
    }
}

// ---------------------------------------------------------------------------
// Apply: fully parallel, prefix given. Bu packed bf16 -> XsB packed bf16.
// ---------------------------------------------------------------------------
__global__ __launch_bounds__(256) void k_scan_apply(const unsigned* __restrict__ Bu,
                                                    unsigned* __restrict__ XsB,
                                                    const float* __restrict__ lambda_bar,
                                                    const float* __restrict__ pref) {
    int gid = blockIdx.x * blockDim.x + threadIdx.x;   // NCHUNK*P threads
    int c = gid >> 9, p = gid & 511;
    const float lr = lambda_bar[2 * p], li = lambda_bar[2 * p + 1];
    float2 x0 = ((const float2*)pref)[(size_t)c * P_DIM + p];
    float xr = x0.x, xi = x0.y;
    const unsigned* bu = Bu + (size_t)c * CHUNK * P_DIM + p;
#pragma unroll 4
    for (int j = 0; j < CHUNK; ++j) {
        unsigned w = bu[(size_t)j * P_DIM];
        float br = bflo2f(w), bi = bfhi2f(w);
        float nxr = lr * xr - li * xi + br;
        float nxi = lr * xi + li * xr + bi;
        xr = nxr; xi = nxi;
        unsigned pk = (unsigned)(unsigned short)f2bf(xr)
                    | ((unsigned)(unsigned short)f2bf(xi) << 16);
        XsB[((size_t)c * CHUNK + j) * P_DIM + p] = pk;
    }
}

// ---------------------------------------------------------------------------
extern "C" void kernel_launch(void* const* d_in, const int* in_sizes, int n_in,
                              void* d_out, int out_size, void* d_ws, size_t ws_size,
                              hipStream_t stream) {
    const float* u        = (const float*)d_in[0];
    const float* Lre      = (const float*)d_in[1];
    const float* Lim      = (const float*)d_in[2];
    const float* Bin      = (const float*)d_in[3];
    const float* Cin      = (const float*)d_in[4];
    const float* Dv       = (const float*)d_in[5];
    const float* log_step = (const float*)d_in[6];
    float* y = (float*)d_out;

    char* w = (char*)d_ws;
    size_t off = 0;
    short* Bcat = (short*)(w + off); off += (size_t)2 * P_DIM * H_DIM * 2;   // 1 MB
    short* Ccat = (short*)(w + off); off += (size_t)2 * P_DIM * H_DIM * 2;   // 1 MB
    float* lamb = (float*)(w + off); off += 2 * P_DIM * 4;
    float* lamN = (float*)(w + off); off += 2 * P_DIM * 4;
    float* S    = (float*)(w + off); off += (size_t)NCHUNK * 2 * P_DIM * 4;  // 1 MB
    float* pref = (float*)(w + off); off += (size_t)NCHUNK * 2 * P_DIM * 4;  // 1 MB
    unsigned* Bu  = (unsigned*)(w + off); off += (size_t)L_DIM * P_DIM * 4;  // 16 MB (packed bf16)
    unsigned* XsB = (unsigned*)(w + off); off += (size_t)L_DIM * P_DIM * 4;  // 16 MB (packed bf16)
    short* u_bf   = (short*)(w + off);   off += (size_t)L_DIM * H_DIM * 2;   // 8 MB

    // prep: discretize + Ccat + u->bf16
    k_prep<<<P_DIM + 1024 + 2048, 256, 0, stream>>>(
        Lre, Lim, Bin, log_step, Cin, u, Bcat, Ccat, u_bf, lamb, lamN);
    // GEMM1 (+fused chunk summaries): Bu[L][2P](bf16 packed) = u_bf * Bcat^T
    k_gemm<128, true, false, true><<<(L_DIM / 128) * ((2 * P_DIM) / 128), 256, 0, stream>>>(
        u_bf, Bcat, (void*)Bu, L_DIM, 2 * P_DIM, H_DIM, (2 * P_DIM) / 128,
        nullptr, nullptr, lamb, S);
    // Combine + apply
    k_scan_combine<<<8, 64, 0, stream>>>(S, lamN, pref);
    k_scan_apply<<<(NCHUNK * P_DIM) / 256, 256, 0, stream>>>(Bu, XsB, lamb, pref);
    // GEMM2: y[L][H] = xs_bf16[L][2P] * Ccat[H][2P]^T + D*u   (BN=64 -> 512 wgs)
    k_gemm<64, false, true, false><<<(L_DIM / 128) * (H_DIM / 64), 256, 0, stream>>>(
        (const short*)XsB, Ccat, (void*)y, L_DIM, H_DIM, 2 * P_DIM, H_DIM / 64,
        Dv, u_bf, nullptr, nullptr);
}